// Round 1
// baseline (1090.181 us; speedup 1.0000x reference)
//
#include <hip/hip_runtime.h>
#include <cmath>

#define Bsz 2
#define Tsz 2048
#define Dsz 1024
#define Hn  8
#define DH  128
#define SCALE 0.08838834764831845f  // 1/sqrt(128)

#define TILE 64
#define BK   16

// ---------------------------------------------------------------------------
// NT GEMM: C[M][N] = A[M][K] * B[N][K]^T + bias[N]
// A row-major (lda), B row-major (ldb) -> both K-contiguous (coalesced).
// 256 threads, 64x64 tile, BK=16, each thread computes 4x4.
// M%64==0, N%64==0, K%16==0 (true for all shapes here).
// ---------------------------------------------------------------------------
__global__ __launch_bounds__(256) void gemm_nt_bias_k(
    const float* __restrict__ A, int lda,
    const float* __restrict__ Bm, int ldb,
    const float* __restrict__ bias,
    float* __restrict__ C, int ldc, int K)
{
    __shared__ float As[BK][TILE + 4];
    __shared__ float Bs[BK][TILE + 4];
    const int tid  = threadIdx.x;
    const int row0 = blockIdx.y * TILE;
    const int col0 = blockIdx.x * TILE;
    const int tx = tid & 15, ty = tid >> 4;
    const int lr = tid >> 2;          // 0..63: tile row loaded by this thread
    const int lk = (tid & 3) * 4;     // k offset 0/4/8/12

    const float* Ag = A  + (size_t)(row0 + lr) * lda + lk;
    const float* Bg = Bm + (size_t)(col0 + lr) * ldb + lk;

    float acc[4][4] = {};
    for (int k0 = 0; k0 < K; k0 += BK) {
        float4 av = *(const float4*)(Ag + k0);
        float4 bv = *(const float4*)(Bg + k0);
        As[lk+0][lr] = av.x; As[lk+1][lr] = av.y; As[lk+2][lr] = av.z; As[lk+3][lr] = av.w;
        Bs[lk+0][lr] = bv.x; Bs[lk+1][lr] = bv.y; Bs[lk+2][lr] = bv.z; Bs[lk+3][lr] = bv.w;
        __syncthreads();
#pragma unroll
        for (int kk = 0; kk < BK; ++kk) {
            float4 a = *(const float4*)&As[kk][ty * 4];
            float4 b = *(const float4*)&Bs[kk][tx * 4];
            const float* ap = (const float*)&a;
            const float* bp = (const float*)&b;
#pragma unroll
            for (int i = 0; i < 4; ++i)
#pragma unroll
                for (int j = 0; j < 4; ++j)
                    acc[i][j] = fmaf(ap[i], bp[j], acc[i][j]);
        }
        __syncthreads();
    }
#pragma unroll
    for (int i = 0; i < 4; ++i) {
        const int gi = row0 + ty * 4 + i;
        float4 c;
        float* cp = (float*)&c;
#pragma unroll
        for (int j = 0; j < 4; ++j)
            cp[j] = acc[i][j] + bias[col0 + tx * 4 + j];
        *(float4*)(C + (size_t)gi * ldc + col0 + tx * 4) = c;
    }
}

// ---------------------------------------------------------------------------
// relpos projection: proj[row][c] = dot(tq[row], table[c]) for c in 0..4
// one wave per row (4 rows per 256-thread block)
// ---------------------------------------------------------------------------
__global__ __launch_bounds__(256) void relproj_k(
    const float* __restrict__ tq, const float* __restrict__ table,
    float* __restrict__ proj)
{
    const int row  = blockIdx.x * 4 + (threadIdx.x >> 6);
    const int lane = threadIdx.x & 63;
    const float* qrow = tq + (size_t)row * Dsz;
    float acc[5] = {0.f, 0.f, 0.f, 0.f, 0.f};
    for (int t = 0; t < Dsz / 64; ++t) {
        const int d = t * 64 + lane;
        const float qv = qrow[d];
#pragma unroll
        for (int c = 0; c < 5; ++c)
            acc[c] = fmaf(qv, table[c * Dsz + d], acc[c]);
    }
#pragma unroll
    for (int c = 0; c < 5; ++c)
        for (int off = 32; off > 0; off >>= 1)
            acc[c] += __shfl_xor(acc[c], off);
    if (lane == 0) {
#pragma unroll
        for (int c = 0; c < 5; ++c)
            proj[(size_t)row * 8 + c] = acc[c];
    }
}

// ---------------------------------------------------------------------------
// logits: Wt[z, i, j] = (q_h[i]·k_h[j] + proj[b,i,clip(j-i)+2]) * SCALE
// z = b*H + h. NT GEMM with K=128 + relpos epilogue. Raw logits (pre-softmax).
// ---------------------------------------------------------------------------
__global__ __launch_bounds__(256) void logits_k(
    const float* __restrict__ tq, const float* __restrict__ tk,
    const float* __restrict__ proj, float* __restrict__ Wt)
{
    __shared__ float As[BK][TILE + 4];
    __shared__ float Bs[BK][TILE + 4];
    const int tid = threadIdx.x;
    const int z = blockIdx.z;
    const int b = z >> 3;   // z / H
    const int h = z & 7;    // z % H
    const int row0 = blockIdx.y * TILE;
    const int col0 = blockIdx.x * TILE;
    const int tx = tid & 15, ty = tid >> 4;
    const int lr = tid >> 2;
    const int lk = (tid & 3) * 4;

    const float* A  = tq + (size_t)b * Tsz * Dsz + h * DH;
    const float* Bm = tk + (size_t)b * Tsz * Dsz + h * DH;
    const float* Ag = A  + (size_t)(row0 + lr) * Dsz + lk;
    const float* Bg = Bm + (size_t)(col0 + lr) * Dsz + lk;

    float acc[4][4] = {};
    for (int k0 = 0; k0 < DH; k0 += BK) {
        float4 av = *(const float4*)(Ag + k0);
        float4 bv = *(const float4*)(Bg + k0);
        As[lk+0][lr] = av.x; As[lk+1][lr] = av.y; As[lk+2][lr] = av.z; As[lk+3][lr] = av.w;
        Bs[lk+0][lr] = bv.x; Bs[lk+1][lr] = bv.y; Bs[lk+2][lr] = bv.z; Bs[lk+3][lr] = bv.w;
        __syncthreads();
#pragma unroll
        for (int kk = 0; kk < BK; ++kk) {
            float4 a = *(const float4*)&As[kk][ty * 4];
            float4 b = *(const float4*)&Bs[kk][tx * 4];
            const float* ap = (const float*)&a;
            const float* bp = (const float*)&b;
#pragma unroll
            for (int i = 0; i < 4; ++i)
#pragma unroll
                for (int j = 0; j < 4; ++j)
                    acc[i][j] = fmaf(ap[i], bp[j], acc[i][j]);
        }
        __syncthreads();
    }
    float* C = Wt + (size_t)z * Tsz * Tsz;
#pragma unroll
    for (int i = 0; i < 4; ++i) {
        const int gi = row0 + ty * 4 + i;
        const float* prow = proj + ((size_t)b * Tsz + gi) * 8;
        float4 c;
        float* cp = (float*)&c;
#pragma unroll
        for (int j = 0; j < 4; ++j) {
            const int gj = col0 + tx * 4 + j;
            int rel = gj - gi;
            rel = rel < -2 ? -2 : (rel > 2 ? 2 : rel);
            cp[j] = (acc[i][j] + prow[rel + 2]) * SCALE;
        }
        *(float4*)(C + (size_t)gi * Tsz + col0 + tx * 4) = c;
    }
}

// ---------------------------------------------------------------------------
// softmax in place over 2048-wide rows; one wave per row, row lives in VGPRs.
// ---------------------------------------------------------------------------
__global__ __launch_bounds__(256) void softmax_k(float* __restrict__ Wt)
{
    const int row  = blockIdx.x * 4 + (threadIdx.x >> 6);
    const int lane = threadIdx.x & 63;
    float4* rp = (float4*)(Wt + (size_t)row * Tsz);
    float4 v[8];
#pragma unroll
    for (int t = 0; t < 8; ++t) v[t] = rp[t * 64 + lane];

    float m = -1e30f;
#pragma unroll
    for (int t = 0; t < 8; ++t)
        m = fmaxf(m, fmaxf(fmaxf(v[t].x, v[t].y), fmaxf(v[t].z, v[t].w)));
    for (int off = 32; off > 0; off >>= 1)
        m = fmaxf(m, __shfl_xor(m, off));

    float s = 0.f;
#pragma unroll
    for (int t = 0; t < 8; ++t) {
        v[t].x = expf(v[t].x - m);
        v[t].y = expf(v[t].y - m);
        v[t].z = expf(v[t].z - m);
        v[t].w = expf(v[t].w - m);
        s += v[t].x + v[t].y + v[t].z + v[t].w;
    }
    for (int off = 32; off > 0; off >>= 1)
        s += __shfl_xor(s, off);

    const float inv = 1.f / s;
#pragma unroll
    for (int t = 0; t < 8; ++t) {
        v[t].x *= inv; v[t].y *= inv; v[t].z *= inv; v[t].w *= inv;
        rp[t * 64 + lane] = v[t];
    }
}

// ---------------------------------------------------------------------------
// PV: ctx_h[i][d] = sum_j Wt[z,i,j] * v_h[j][d]   (NN GEMM, K=2048, N=128)
// ---------------------------------------------------------------------------
__global__ __launch_bounds__(256) void pv_k(
    const float* __restrict__ Wt, const float* __restrict__ tv,
    float* __restrict__ ctx)
{
    __shared__ float As[BK][TILE + 4];
    __shared__ float Bs[BK][TILE + 4];
    const int tid = threadIdx.x;
    const int z = blockIdx.z;
    const int b = z >> 3;
    const int h = z & 7;
    const int row0 = blockIdx.y * TILE;   // i tile
    const int col0 = blockIdx.x * TILE;   // d tile (0 or 64)
    const int tx = tid & 15, ty = tid >> 4;
    const int lr = tid >> 2;
    const int lk = (tid & 3) * 4;
    const int kr = tid >> 4;              // 0..15 (B-tile k row)
    const int n4 = (tid & 15) * 4;        // B-tile col offset

    const float* A  = Wt + (size_t)z * Tsz * Tsz;
    const float* Bv = tv + (size_t)b * Tsz * Dsz + h * DH;

    float acc[4][4] = {};
    for (int k0 = 0; k0 < Tsz; k0 += BK) {
        float4 av = *(const float4*)(A + (size_t)(row0 + lr) * Tsz + k0 + lk);
        float4 bv = *(const float4*)(Bv + (size_t)(k0 + kr) * Dsz + col0 + n4);
        As[lk+0][lr] = av.x; As[lk+1][lr] = av.y; As[lk+2][lr] = av.z; As[lk+3][lr] = av.w;
        *(float4*)&Bs[kr][n4] = bv;
        __syncthreads();
#pragma unroll
        for (int kk = 0; kk < BK; ++kk) {
            float4 a = *(const float4*)&As[kk][ty * 4];
            float4 b = *(const float4*)&Bs[kk][tx * 4];
            const float* ap = (const float*)&a;
            const float* bp = (const float*)&b;
#pragma unroll
            for (int i = 0; i < 4; ++i)
#pragma unroll
                for (int j = 0; j < 4; ++j)
                    acc[i][j] = fmaf(ap[i], bp[j], acc[i][j]);
        }
        __syncthreads();
    }
    float* C = ctx + (size_t)b * Tsz * Dsz + h * DH;
#pragma unroll
    for (int i = 0; i < 4; ++i) {
        const int gi = row0 + ty * 4 + i;
        float4 c;
        float* cp = (float*)&c;
#pragma unroll
        for (int j = 0; j < 4; ++j) cp[j] = acc[i][j];
        *(float4*)(C + (size_t)gi * Dsz + col0 + tx * 4) = c;
    }
}

// ---------------------------------------------------------------------------
extern "C" void kernel_launch(void* const* d_in, const int* in_sizes, int n_in,
                              void* d_out, int out_size, void* d_ws, size_t ws_size,
                              hipStream_t stream)
{
    const float* query  = (const float*)d_in[0];
    const float* keys   = (const float*)d_in[1];
    const float* values = (const float*)d_in[2];
    const float* Wq = (const float*)d_in[3];
    const float* bq = (const float*)d_in[4];
    const float* Wk = (const float*)d_in[5];
    const float* bk = (const float*)d_in[6];
    const float* Wv = (const float*)d_in[7];
    const float* bv = (const float*)d_in[8];
    const float* Wo = (const float*)d_in[9];
    const float* bo = (const float*)d_in[10];
    const float* table = (const float*)d_in[11];

    float* out     = (float*)d_out;                          // B*T*D
    float* weights = out + (size_t)Bsz * Tsz * Dsz;          // B*H*T*T

    float* ws  = (float*)d_ws;
    float* tq  = ws;
    float* tk  = tq  + (size_t)Bsz * Tsz * Dsz;
    float* tv  = tk  + (size_t)Bsz * Tsz * Dsz;
    float* ctx = tv  + (size_t)Bsz * Tsz * Dsz;
    float* proj = ctx + (size_t)Bsz * Tsz * Dsz;             // B*T*8 floats

    const dim3 blk(256);
    const int MR = Bsz * Tsz;   // 4096 rows for projection GEMMs

    // Q/K/V projections: [4096,1024] = X @ W^T + b
    gemm_nt_bias_k<<<dim3(Dsz / TILE, MR / TILE), blk, 0, stream>>>(
        query, Dsz, Wq, Dsz, bq, tq, Dsz, Dsz);
    gemm_nt_bias_k<<<dim3(Dsz / TILE, MR / TILE), blk, 0, stream>>>(
        keys, Dsz, Wk, Dsz, bk, tk, Dsz, Dsz);
    gemm_nt_bias_k<<<dim3(Dsz / TILE, MR / TILE), blk, 0, stream>>>(
        values, Dsz, Wv, Dsz, bv, tv, Dsz, Dsz);

    // relpos projection (needs tq)
    relproj_k<<<dim3(MR / 4), blk, 0, stream>>>(tq, table, proj);

    // raw logits (+relpos bias, scaled) -> weights buffer
    logits_k<<<dim3(Tsz / TILE, Tsz / TILE, Bsz * Hn), blk, 0, stream>>>(
        tq, tk, proj, weights);

    // softmax in place
    softmax_k<<<dim3(Bsz * Hn * Tsz / 4), blk, 0, stream>>>(weights);

    // PV
    pv_k<<<dim3(DH / TILE, Tsz / TILE, Bsz * Hn), blk, 0, stream>>>(
        weights, tv, ctx);

    // output projection -> d_out
    gemm_nt_bias_k<<<dim3(Dsz / TILE, MR / TILE), blk, 0, stream>>>(
        ctx, Dsz, Wo, Dsz, bo, out, Dsz, Dsz);
}

// Round 2
// 364.911 us; speedup vs baseline: 2.9875x; 2.9875x over previous
//
#include <hip/hip_runtime.h>
#include <hip/hip_bf16.h>
#include <cmath>

#define Bsz 2
#define Tsz 2048
#define Dsz 1024
#define Hn  8
#define DH  128
#define SCALE 0.08838834764831845f  // 1/sqrt(128)

typedef __attribute__((ext_vector_type(8))) short short8;
typedef __attribute__((ext_vector_type(4))) short short4v;
typedef __attribute__((ext_vector_type(4))) float f32x4;
typedef __hip_bfloat16 bf16;

#define LDT 40   // LDS row stride in elems (32 data + 8 pad -> 80B, 16B-aligned rows)

__device__ __forceinline__ float bf2f(unsigned short u) {
    return __uint_as_float(((unsigned)u) << 16);
}
__device__ __forceinline__ unsigned short f2bf(float f) {
    bf16 h = __float2bfloat16(f);
    return *(unsigned short*)&h;
}

// ---------------------------------------------------------------------------
// fp32 -> bf16 conversion, 7 tensors in one launch (blockIdx.y = job)
// ---------------------------------------------------------------------------
struct CvtJob { const float* s; bf16* d; int n; };
struct CvtArgs { CvtJob j[7]; };

__global__ __launch_bounds__(256) void cvt_k(CvtArgs a) {
    CvtJob job = a.j[blockIdx.y];
    int idx = (blockIdx.x * 256 + threadIdx.x) * 8;
    const int stride = gridDim.x * 256 * 8;
    for (; idx < job.n; idx += stride) {
        float4 f0 = *(const float4*)(job.s + idx);
        float4 f1 = *(const float4*)(job.s + idx + 4);
        short8 o;
        o[0] = (short)f2bf(f0.x); o[1] = (short)f2bf(f0.y);
        o[2] = (short)f2bf(f0.z); o[3] = (short)f2bf(f0.w);
        o[4] = (short)f2bf(f1.x); o[5] = (short)f2bf(f1.y);
        o[6] = (short)f2bf(f1.z); o[7] = (short)f2bf(f1.w);
        *(short8*)(job.d + idx) = o;
    }
}

// ---------------------------------------------------------------------------
// MFMA fragment compute: 128x128 tile, 4 waves (2x2 of 64x64), 16 MFMA/K-step
// A-frag: row = lane&15, k-block = lane>>4 (contiguous-8; any consistent
// k-permutation cancels between A and B). C/D: col=lane&15, row=(lane>>4)*4+r.
// ---------------------------------------------------------------------------
__device__ __forceinline__ void mfma_step(const bf16* As, const bf16* Bs,
                                          f32x4 acc[4][4],
                                          int wr, int wc, int fr, int g)
{
    short8 af[4], bfv[4];
#pragma unroll
    for (int m = 0; m < 4; ++m)
        af[m] = *(const short8*)(As + (wr * 64 + m * 16 + fr) * LDT + g * 8);
#pragma unroll
    for (int n = 0; n < 4; ++n)
        bfv[n] = *(const short8*)(Bs + (wc * 64 + n * 16 + fr) * LDT + g * 8);
#pragma unroll
    for (int m = 0; m < 4; ++m)
#pragma unroll
        for (int n = 0; n < 4; ++n)
            acc[m][n] = __builtin_amdgcn_mfma_f32_16x16x32_bf16(
                af[m], bfv[n], acc[m][n], 0, 0, 0);
}

// ---------------------------------------------------------------------------
// Generic NT GEMM: C[M][N] = A[M][K] @ B[N][K]^T + bias.  A,B bf16.
// OUTBF=1 -> bf16 C, OUTBF=0 -> fp32 C.  M%128==0, N%128==0, K%32==0.
// ---------------------------------------------------------------------------
template <int OUTBF>
__global__ __launch_bounds__(256) void gemm_nt_k(
    const bf16* __restrict__ A, int lda,
    const bf16* __restrict__ B, int ldb,
    const float* __restrict__ bias,
    void* __restrict__ Cv, int ldc, int K)
{
    __shared__ bf16 As[128 * LDT];
    __shared__ bf16 Bs[128 * LDT];
    const int tid = threadIdx.x;
    const int row0 = blockIdx.y * 128;
    const int col0 = blockIdx.x * 128;
    const int lane = tid & 63;
    const int w = tid >> 6, wr = w >> 1, wc = w & 1;
    const int fr = lane & 15, g = lane >> 4;

    const int c0 = tid, c1 = tid + 256;
    const int r0 = c0 >> 2, kc0 = (c0 & 3) * 8;
    const int r1 = c1 >> 2, kc1 = (c1 & 3) * 8;
    const bf16* Ag0 = A + (size_t)(row0 + r0) * lda + kc0;
    const bf16* Ag1 = A + (size_t)(row0 + r1) * lda + kc1;
    const bf16* Bg0 = B + (size_t)(col0 + r0) * ldb + kc0;
    const bf16* Bg1 = B + (size_t)(col0 + r1) * ldb + kc1;

    f32x4 acc[4][4];
    const f32x4 vz = {0.f, 0.f, 0.f, 0.f};
#pragma unroll
    for (int m = 0; m < 4; ++m)
#pragma unroll
        for (int n = 0; n < 4; ++n) acc[m][n] = vz;

    short8 va0 = *(const short8*)Ag0;
    short8 va1 = *(const short8*)Ag1;
    short8 vb0 = *(const short8*)Bg0;
    short8 vb1 = *(const short8*)Bg1;

    for (int k0 = 0; k0 < K; k0 += 32) {
        __syncthreads();
        *(short8*)(As + r0 * LDT + kc0) = va0;
        *(short8*)(As + r1 * LDT + kc1) = va1;
        *(short8*)(Bs + r0 * LDT + kc0) = vb0;
        *(short8*)(Bs + r1 * LDT + kc1) = vb1;
        __syncthreads();
        if (k0 + 32 < K) {
            va0 = *(const short8*)(Ag0 + k0 + 32);
            va1 = *(const short8*)(Ag1 + k0 + 32);
            vb0 = *(const short8*)(Bg0 + k0 + 32);
            vb1 = *(const short8*)(Bg1 + k0 + 32);
        }
        mfma_step(As, Bs, acc, wr, wc, fr, g);
    }

#pragma unroll
    for (int m = 0; m < 4; ++m) {
#pragma unroll
        for (int r = 0; r < 4; ++r) {
            const int gi = row0 + wr * 64 + m * 16 + g * 4 + r;
#pragma unroll
            for (int n = 0; n < 4; ++n) {
                const int gj = col0 + wc * 64 + n * 16 + fr;
                float x = acc[m][n][r] + bias[gj];
                if (OUTBF)
                    ((bf16*)Cv)[(size_t)gi * ldc + gj] = __float2bfloat16(x);
                else
                    ((float*)Cv)[(size_t)gi * ldc + gj] = x;
            }
        }
    }
}

// ---------------------------------------------------------------------------
// relpos projection: proj[row][c] = dot(tq[row], table[c]), c in 0..4
// ---------------------------------------------------------------------------
__global__ __launch_bounds__(256) void relproj_k(
    const bf16* __restrict__ tq, const float* __restrict__ table,
    float* __restrict__ proj)
{
    const int row  = blockIdx.x * 4 + (threadIdx.x >> 6);
    const int lane = threadIdx.x & 63;
    const bf16* qrow = tq + (size_t)row * Dsz;
    float acc[5] = {0.f, 0.f, 0.f, 0.f, 0.f};
#pragma unroll
    for (int t = 0; t < 4; ++t) {
        const int d = t * 256 + lane * 4;
        short4v q4 = *(const short4v*)(qrow + d);
        float qv[4];
#pragma unroll
        for (int q = 0; q < 4; ++q) qv[q] = bf2f((unsigned short)q4[q]);
#pragma unroll
        for (int c = 0; c < 5; ++c) {
            float4 t4 = *(const float4*)(table + c * Dsz + d);
            acc[c] = fmaf(qv[0], t4.x, acc[c]);
            acc[c] = fmaf(qv[1], t4.y, acc[c]);
            acc[c] = fmaf(qv[2], t4.z, acc[c]);
            acc[c] = fmaf(qv[3], t4.w, acc[c]);
        }
    }
#pragma unroll
    for (int c = 0; c < 5; ++c)
        for (int off = 32; off > 0; off >>= 1)
            acc[c] += __shfl_xor(acc[c], off);
    if (lane == 0) {
#pragma unroll
        for (int c = 0; c < 5; ++c)
            proj[(size_t)row * 8 + c] = acc[c];
    }
}

// ---------------------------------------------------------------------------
// logits: Wt[z,i,j] = (q_h[i]·k_h[j] + proj[b,i,clip(j-i)+2]) * SCALE  (fp32)
// ---------------------------------------------------------------------------
__global__ __launch_bounds__(256) void logits_k(
    const bf16* __restrict__ tq, const bf16* __restrict__ tk,
    const float* __restrict__ proj, float* __restrict__ Wt)
{
    __shared__ bf16 As[128 * LDT];
    __shared__ bf16 Bs[128 * LDT];
    const int tid = threadIdx.x;
    const int z = blockIdx.z, b = z >> 3, h = z & 7;
    const int row0 = blockIdx.y * 128;
    const int col0 = blockIdx.x * 128;
    const int lane = tid & 63;
    const int w = tid >> 6, wr = w >> 1, wc = w & 1;
    const int fr = lane & 15, g = lane >> 4;

    const bf16* A = tq + (size_t)b * Tsz * Dsz + h * DH;
    const bf16* B = tk + (size_t)b * Tsz * Dsz + h * DH;

    const int c0 = tid, c1 = tid + 256;
    const int r0 = c0 >> 2, kc0 = (c0 & 3) * 8;
    const int r1 = c1 >> 2, kc1 = (c1 & 3) * 8;
    const bf16* Ag0 = A + (size_t)(row0 + r0) * Dsz + kc0;
    const bf16* Ag1 = A + (size_t)(row0 + r1) * Dsz + kc1;
    const bf16* Bg0 = B + (size_t)(col0 + r0) * Dsz + kc0;
    const bf16* Bg1 = B + (size_t)(col0 + r1) * Dsz + kc1;

    f32x4 acc[4][4];
    const f32x4 vz = {0.f, 0.f, 0.f, 0.f};
#pragma unroll
    for (int m = 0; m < 4; ++m)
#pragma unroll
        for (int n = 0; n < 4; ++n) acc[m][n] = vz;

    short8 va0 = *(const short8*)Ag0;
    short8 va1 = *(const short8*)Ag1;
    short8 vb0 = *(const short8*)Bg0;
    short8 vb1 = *(const short8*)Bg1;

    for (int k0 = 0; k0 < DH; k0 += 32) {
        __syncthreads();
        *(short8*)(As + r0 * LDT + kc0) = va0;
        *(short8*)(As + r1 * LDT + kc1) = va1;
        *(short8*)(Bs + r0 * LDT + kc0) = vb0;
        *(short8*)(Bs + r1 * LDT + kc1) = vb1;
        __syncthreads();
        if (k0 + 32 < DH) {
            va0 = *(const short8*)(Ag0 + k0 + 32);
            va1 = *(const short8*)(Ag1 + k0 + 32);
            vb0 = *(const short8*)(Bg0 + k0 + 32);
            vb1 = *(const short8*)(Bg1 + k0 + 32);
        }
        mfma_step(As, Bs, acc, wr, wc, fr, g);
    }

    float* C = Wt + (size_t)z * Tsz * Tsz;
#pragma unroll
    for (int m = 0; m < 4; ++m) {
#pragma unroll
        for (int r = 0; r < 4; ++r) {
            const int gi = row0 + wr * 64 + m * 16 + g * 4 + r;
            const float* prow = proj + (size_t)(b * Tsz + gi) * 8;
#pragma unroll
            for (int n = 0; n < 4; ++n) {
                const int gj = col0 + wc * 64 + n * 16 + fr;
                int rel = gj - gi;
                rel = rel < -2 ? -2 : (rel > 2 ? 2 : rel);
                C[(size_t)gi * Tsz + gj] = (acc[m][n][r] + prow[rel + 2]) * SCALE;
            }
        }
    }
}

// ---------------------------------------------------------------------------
// softmax in place over 2048-wide fp32 rows; one wave per row
// ---------------------------------------------------------------------------
__global__ __launch_bounds__(256) void softmax_k(float* __restrict__ Wt)
{
    const int row  = blockIdx.x * 4 + (threadIdx.x >> 6);
    const int lane = threadIdx.x & 63;
    float4* rp = (float4*)(Wt + (size_t)row * Tsz);
    float4 v[8];
#pragma unroll
    for (int t = 0; t < 8; ++t) v[t] = rp[t * 64 + lane];

    float m = -1e30f;
#pragma unroll
    for (int t = 0; t < 8; ++t)
        m = fmaxf(m, fmaxf(fmaxf(v[t].x, v[t].y), fmaxf(v[t].z, v[t].w)));
    for (int off = 32; off > 0; off >>= 1)
        m = fmaxf(m, __shfl_xor(m, off));

    float s = 0.f;
#pragma unroll
    for (int t = 0; t < 8; ++t) {
        v[t].x = expf(v[t].x - m);
        v[t].y = expf(v[t].y - m);
        v[t].z = expf(v[t].z - m);
        v[t].w = expf(v[t].w - m);
        s += v[t].x + v[t].y + v[t].z + v[t].w;
    }
    for (int off = 32; off > 0; off >>= 1)
        s += __shfl_xor(s, off);

    const float inv = 1.f / s;
#pragma unroll
    for (int t = 0; t < 8; ++t) {
        v[t].x *= inv; v[t].y *= inv; v[t].z *= inv; v[t].w *= inv;
        rp[t * 64 + lane] = v[t];
    }
}

// ---------------------------------------------------------------------------
// transpose V: tv[b*T + j][h*DH + d]  ->  vt[(b*8+h)*DH + d][j]
// ---------------------------------------------------------------------------
__global__ __launch_bounds__(256) void transpose_v_k(
    const bf16* __restrict__ tv, bf16* __restrict__ vt)
{
    __shared__ short Tsh[64 * 72];
    const int j0 = blockIdx.x * 64, d0 = blockIdx.y * 64, b = blockIdx.z;
    const int tid = threadIdx.x;
#pragma unroll
    for (int i = 0; i < 2; ++i) {
        const int c = tid + i * 256;
        const int r = c >> 3, kc = (c & 7) * 8;
        short8 v = *(const short8*)(tv + (size_t)(b * Tsz + j0 + r) * Dsz + d0 + kc);
#pragma unroll
        for (int q = 0; q < 8; ++q)
            Tsh[(kc + q) * 72 + r] = v[q];   // Tsh[d][j]
    }
    __syncthreads();
    const int h = d0 >> 7, dbase = d0 & 127;
#pragma unroll
    for (int i = 0; i < 2; ++i) {
        const int c = tid + i * 256;
        const int dr = c >> 3, jc = (c & 7) * 8;
        short8 o = *(const short8*)(Tsh + dr * 72 + jc);
        *(short8*)(vt + ((size_t)(b * Hn + h) * DH + dbase + dr) * Tsz + j0 + jc) = o;
    }
}

// ---------------------------------------------------------------------------
// PV: ctx[b*T+i][h*DH+d] = sum_j P[z,i,j] * vt[z,d,j]
// A staged from fp32 weights with on-the-fly bf16 convert; B = vt bf16 NT.
// ---------------------------------------------------------------------------
__global__ __launch_bounds__(256) void pv_k(
    const float* __restrict__ Wt, const bf16* __restrict__ vt,
    bf16* __restrict__ ctx)
{
    __shared__ bf16 As[128 * LDT];
    __shared__ bf16 Bs[128 * LDT];
    const int tid = threadIdx.x;
    const int z = blockIdx.z, b = z >> 3, h = z & 7;
    const int row0 = blockIdx.y * 128;
    const int lane = tid & 63;
    const int w = tid >> 6, wr = w >> 1, wc = w & 1;
    const int fr = lane & 15, g = lane >> 4;

    const float* Aw = Wt + (size_t)z * Tsz * Tsz;
    const bf16*  Bv = vt + (size_t)z * DH * Tsz;

    const int c0 = tid, c1 = tid + 256;
    const int r0 = c0 >> 2, kc0 = (c0 & 3) * 8;
    const int r1 = c1 >> 2, kc1 = (c1 & 3) * 8;
    const float* Ag0 = Aw + (size_t)(row0 + r0) * Tsz + kc0;
    const float* Ag1 = Aw + (size_t)(row0 + r1) * Tsz + kc1;
    const bf16*  Bg0 = Bv + (size_t)r0 * Tsz + kc0;
    const bf16*  Bg1 = Bv + (size_t)r1 * Tsz + kc1;

    f32x4 acc[4][4];
    const f32x4 vz = {0.f, 0.f, 0.f, 0.f};
#pragma unroll
    for (int m = 0; m < 4; ++m)
#pragma unroll
        for (int n = 0; n < 4; ++n) acc[m][n] = vz;

    float4 fa00 = *(const float4*)Ag0;
    float4 fa01 = *(const float4*)(Ag0 + 4);
    float4 fa10 = *(const float4*)Ag1;
    float4 fa11 = *(const float4*)(Ag1 + 4);
    short8 vb0 = *(const short8*)Bg0;
    short8 vb1 = *(const short8*)Bg1;

    for (int k0 = 0; k0 < Tsz; k0 += 32) {
        short8 sa0, sa1;
        sa0[0]=(short)f2bf(fa00.x); sa0[1]=(short)f2bf(fa00.y);
        sa0[2]=(short)f2bf(fa00.z); sa0[3]=(short)f2bf(fa00.w);
        sa0[4]=(short)f2bf(fa01.x); sa0[5]=(short)f2bf(fa01.y);
        sa0[6]=(short)f2bf(fa01.z); sa0[7]=(short)f2bf(fa01.w);
        sa1[0]=(short)f2bf(fa10.x); sa1[1]=(short)f2bf(fa10.y);
        sa1[2]=(short)f2bf(fa10.z); sa1[3]=(short)f2bf(fa10.w);
        sa1[4]=(short)f2bf(fa11.x); sa1[5]=(short)f2bf(fa11.y);
        sa1[6]=(short)f2bf(fa11.z); sa1[7]=(short)f2bf(fa11.w);
        __syncthreads();
        *(short8*)(As + r0 * LDT + kc0) = sa0;
        *(short8*)(As + r1 * LDT + kc1) = sa1;
        *(short8*)(Bs + r0 * LDT + kc0) = vb0;
        *(short8*)(Bs + r1 * LDT + kc1) = vb1;
        __syncthreads();
        if (k0 + 32 < Tsz) {
            fa00 = *(const float4*)(Ag0 + k0 + 32);
            fa01 = *(const float4*)(Ag0 + k0 + 36);
            fa10 = *(const float4*)(Ag1 + k0 + 32);
            fa11 = *(const float4*)(Ag1 + k0 + 36);
            vb0 = *(const short8*)(Bg0 + k0 + 32);
            vb1 = *(const short8*)(Bg1 + k0 + 32);
        }
        mfma_step(As, Bs, acc, wr, wc, fr, g);
    }

    bf16* C = ctx + (size_t)(b * Tsz) * Dsz + h * DH;
#pragma unroll
    for (int m = 0; m < 4; ++m) {
#pragma unroll
        for (int r = 0; r < 4; ++r) {
            const int gi = row0 + wr * 64 + m * 16 + g * 4 + r;
#pragma unroll
            for (int n = 0; n < 4; ++n) {
                const int gj = wc * 64 + n * 16 + fr;
                C[(size_t)gi * Dsz + gj] = __float2bfloat16(acc[m][n][r]);
            }
        }
    }
}

// ---------------------------------------------------------------------------
extern "C" void kernel_launch(void* const* d_in, const int* in_sizes, int n_in,
                              void* d_out, int out_size, void* d_ws, size_t ws_size,
                              hipStream_t stream)
{
    const float* query  = (const float*)d_in[0];
    const float* keys   = (const float*)d_in[1];
    const float* values = (const float*)d_in[2];
    const float* Wq = (const float*)d_in[3];
    const float* bq = (const float*)d_in[4];
    const float* Wk = (const float*)d_in[5];
    const float* bk = (const float*)d_in[6];
    const float* Wv = (const float*)d_in[7];
    const float* bv = (const float*)d_in[8];
    const float* Wo = (const float*)d_in[9];
    const float* bo = (const float*)d_in[10];
    const float* table = (const float*)d_in[11];

    float* out     = (float*)d_out;                      // B*T*D fp32
    float* weights = out + (size_t)Bsz * Tsz * Dsz;      // B*H*T*T fp32

    const size_t NTD = (size_t)Bsz * Tsz * Dsz;          // 4M elems
    char* wp = (char*)d_ws;
    bf16* qb  = (bf16*)(wp);                              // later reused as vt
    bf16* kb  = (bf16*)(wp + 8  * 1024 * 1024);           // later reused as ctx
    bf16* vb  = (bf16*)(wp + 16 * 1024 * 1024);
    bf16* tq  = (bf16*)(wp + 24 * 1024 * 1024);
    bf16* tk  = (bf16*)(wp + 32 * 1024 * 1024);
    bf16* tv  = (bf16*)(wp + 40 * 1024 * 1024);
    bf16* Wqb = (bf16*)(wp + 48 * 1024 * 1024);
    bf16* Wkb = (bf16*)(wp + 50 * 1024 * 1024);
    bf16* Wvb = (bf16*)(wp + 52 * 1024 * 1024);
    bf16* Wob = (bf16*)(wp + 54 * 1024 * 1024);
    float* proj = (float*)(wp + 56 * 1024 * 1024);        // 4096*8 fp32
    bf16* vt  = qb;
    bf16* ctx = kb;

    const dim3 blk(256);

    CvtArgs ca;
    ca.j[0] = { query,  qb,  (int)NTD };
    ca.j[1] = { keys,   kb,  (int)NTD };
    ca.j[2] = { values, vb,  (int)NTD };
    ca.j[3] = { Wq, Wqb, Dsz * Dsz };
    ca.j[4] = { Wk, Wkb, Dsz * Dsz };
    ca.j[5] = { Wv, Wvb, Dsz * Dsz };
    ca.j[6] = { Wo, Wob, Dsz * Dsz };
    cvt_k<<<dim3(1024, 7), blk, 0, stream>>>(ca);

    // Q/K/V projections (bf16 out)
    gemm_nt_k<1><<<dim3(Dsz / 128, Bsz * Tsz / 128), blk, 0, stream>>>(
        qb, Dsz, Wqb, Dsz, bq, tq, Dsz, Dsz);
    gemm_nt_k<1><<<dim3(Dsz / 128, Bsz * Tsz / 128), blk, 0, stream>>>(
        kb, Dsz, Wkb, Dsz, bk, tk, Dsz, Dsz);
    gemm_nt_k<1><<<dim3(Dsz / 128, Bsz * Tsz / 128), blk, 0, stream>>>(
        vb, Dsz, Wvb, Dsz, bv, tv, Dsz, Dsz);

    relproj_k<<<dim3(Bsz * Tsz / 4), blk, 0, stream>>>(tq, table, proj);

    // raw logits (fp32, with relpos bias + scale) -> weights buffer
    logits_k<<<dim3(Tsz / 128, Tsz / 128, Bsz * Hn), blk, 0, stream>>>(
        tq, tk, proj, weights);

    // V transpose (tv dead after this; vt overwrites qb which is dead)
    transpose_v_k<<<dim3(Tsz / 64, Dsz / 64, Bsz), blk, 0, stream>>>(tv, vt);

    softmax_k<<<dim3(Bsz * Hn * Tsz / 4), blk, 0, stream>>>(weights);

    pv_k<<<dim3(1, Tsz / 128, Bsz * Hn), blk, 0, stream>>>(weights, vt, ctx);

    // output projection (fp32 out + bias)
    gemm_nt_k<0><<<dim3(Dsz / 128, Bsz * Tsz / 128), blk, 0, stream>>>(
        ctx, Dsz, Wob, Dsz, bo, out, Dsz, Dsz);
}

// Round 3
// 267.049 us; speedup vs baseline: 4.0823x; 1.3665x over previous
//
#include <hip/hip_runtime.h>
#include <hip/hip_bf16.h>
#include <cmath>

#define Bsz 2
#define Tsz 2048
#define Dsz 1024
#define Hn  8
#define DH  128
#define SCALE 0.08838834764831845f  // 1/sqrt(128)

typedef __attribute__((ext_vector_type(8))) short short8;
typedef __attribute__((ext_vector_type(4))) short short4v;
typedef __attribute__((ext_vector_type(4))) float f32x4;
typedef __hip_bfloat16 bf16;

#define LDT 40   // GEMM LDS row stride (32 data + 8 pad)
#define LDK 136  // flash LDS row stride for 128-wide tiles (128 + 8 pad)

__device__ __forceinline__ float bf2f(unsigned short u) {
    return __uint_as_float(((unsigned)u) << 16);
}
__device__ __forceinline__ unsigned short f2bf(float f) {
    bf16 h = __float2bfloat16(f);
    return *(unsigned short*)&h;
}

// ---------------------------------------------------------------------------
// fp32 -> bf16 conversion, 7 tensors in one launch (blockIdx.y = job)
// ---------------------------------------------------------------------------
struct CvtJob { const float* s; bf16* d; int n; };
struct CvtArgs { CvtJob j[7]; };

__global__ __launch_bounds__(256) void cvt_k(CvtArgs a) {
    CvtJob job = a.j[blockIdx.y];
    int idx = (blockIdx.x * 256 + threadIdx.x) * 8;
    const int stride = gridDim.x * 256 * 8;
    for (; idx < job.n; idx += stride) {
        float4 f0 = *(const float4*)(job.s + idx);
        float4 f1 = *(const float4*)(job.s + idx + 4);
        short8 o;
        o[0] = (short)f2bf(f0.x); o[1] = (short)f2bf(f0.y);
        o[2] = (short)f2bf(f0.z); o[3] = (short)f2bf(f0.w);
        o[4] = (short)f2bf(f1.x); o[5] = (short)f2bf(f1.y);
        o[6] = (short)f2bf(f1.z); o[7] = (short)f2bf(f1.w);
        *(short8*)(job.d + idx) = o;
    }
}

// ---------------------------------------------------------------------------
// MFMA fragment compute: 128x128 tile, 4 waves (2x2 of 64x64)
// ---------------------------------------------------------------------------
__device__ __forceinline__ void mfma_step(const bf16* As, const bf16* Bs,
                                          f32x4 acc[4][4],
                                          int wr, int wc, int fr, int g)
{
    short8 af[4], bfv[4];
#pragma unroll
    for (int m = 0; m < 4; ++m)
        af[m] = *(const short8*)(As + (wr * 64 + m * 16 + fr) * LDT + g * 8);
#pragma unroll
    for (int n = 0; n < 4; ++n)
        bfv[n] = *(const short8*)(Bs + (wc * 64 + n * 16 + fr) * LDT + g * 8);
#pragma unroll
    for (int m = 0; m < 4; ++m)
#pragma unroll
        for (int n = 0; n < 4; ++n)
            acc[m][n] = __builtin_amdgcn_mfma_f32_16x16x32_bf16(
                af[m], bfv[n], acc[m][n], 0, 0, 0);
}

// ---------------------------------------------------------------------------
// Generic NT GEMM: C[M][N] = A[M][K] @ B[N][K]^T + bias.  A,B bf16.
// ---------------------------------------------------------------------------
template <int OUTBF>
__global__ __launch_bounds__(256) void gemm_nt_k(
    const bf16* __restrict__ A, int lda,
    const bf16* __restrict__ B, int ldb,
    const float* __restrict__ bias,
    void* __restrict__ Cv, int ldc, int K)
{
    __shared__ __align__(16) bf16 As[128 * LDT];
    __shared__ __align__(16) bf16 Bs[128 * LDT];
    const int tid = threadIdx.x;
    const int row0 = blockIdx.y * 128;
    const int col0 = blockIdx.x * 128;
    const int lane = tid & 63;
    const int w = tid >> 6, wr = w >> 1, wc = w & 1;
    const int fr = lane & 15, g = lane >> 4;

    const int c0 = tid, c1 = tid + 256;
    const int r0 = c0 >> 2, kc0 = (c0 & 3) * 8;
    const int r1 = c1 >> 2, kc1 = (c1 & 3) * 8;
    const bf16* Ag0 = A + (size_t)(row0 + r0) * lda + kc0;
    const bf16* Ag1 = A + (size_t)(row0 + r1) * lda + kc1;
    const bf16* Bg0 = B + (size_t)(col0 + r0) * ldb + kc0;
    const bf16* Bg1 = B + (size_t)(col0 + r1) * ldb + kc1;

    f32x4 acc[4][4];
    const f32x4 vz = {0.f, 0.f, 0.f, 0.f};
#pragma unroll
    for (int m = 0; m < 4; ++m)
#pragma unroll
        for (int n = 0; n < 4; ++n) acc[m][n] = vz;

    short8 va0 = *(const short8*)Ag0;
    short8 va1 = *(const short8*)Ag1;
    short8 vb0 = *(const short8*)Bg0;
    short8 vb1 = *(const short8*)Bg1;

    for (int k0 = 0; k0 < K; k0 += 32) {
        __syncthreads();
        *(short8*)(As + r0 * LDT + kc0) = va0;
        *(short8*)(As + r1 * LDT + kc1) = va1;
        *(short8*)(Bs + r0 * LDT + kc0) = vb0;
        *(short8*)(Bs + r1 * LDT + kc1) = vb1;
        __syncthreads();
        if (k0 + 32 < K) {
            va0 = *(const short8*)(Ag0 + k0 + 32);
            va1 = *(const short8*)(Ag1 + k0 + 32);
            vb0 = *(const short8*)(Bg0 + k0 + 32);
            vb1 = *(const short8*)(Bg1 + k0 + 32);
        }
        mfma_step(As, Bs, acc, wr, wc, fr, g);
    }

#pragma unroll
    for (int m = 0; m < 4; ++m) {
#pragma unroll
        for (int r = 0; r < 4; ++r) {
            const int gi = row0 + wr * 64 + m * 16 + g * 4 + r;
#pragma unroll
            for (int n = 0; n < 4; ++n) {
                const int gj = col0 + wc * 64 + n * 16 + fr;
                float x = acc[m][n][r] + bias[gj];
                if (OUTBF)
                    ((bf16*)Cv)[(size_t)gi * ldc + gj] = __float2bfloat16(x);
                else
                    ((float*)Cv)[(size_t)gi * ldc + gj] = x;
            }
        }
    }
}

// ---------------------------------------------------------------------------
// relpos projection: proj[row][c] = dot(tq[row], table[c]), c in 0..4
// ---------------------------------------------------------------------------
__global__ __launch_bounds__(256) void relproj_k(
    const bf16* __restrict__ tq, const float* __restrict__ table,
    float* __restrict__ proj)
{
    const int row  = blockIdx.x * 4 + (threadIdx.x >> 6);
    const int lane = threadIdx.x & 63;
    const bf16* qrow = tq + (size_t)row * Dsz;
    float acc[5] = {0.f, 0.f, 0.f, 0.f, 0.f};
#pragma unroll
    for (int t = 0; t < 4; ++t) {
        const int d = t * 256 + lane * 4;
        short4v q4 = *(const short4v*)(qrow + d);
        float qv[4];
#pragma unroll
        for (int q = 0; q < 4; ++q) qv[q] = bf2f((unsigned short)q4[q]);
#pragma unroll
        for (int c = 0; c < 5; ++c) {
            float4 t4 = *(const float4*)(table + c * Dsz + d);
            acc[c] = fmaf(qv[0], t4.x, acc[c]);
            acc[c] = fmaf(qv[1], t4.y, acc[c]);
            acc[c] = fmaf(qv[2], t4.z, acc[c]);
            acc[c] = fmaf(qv[3], t4.w, acc[c]);
        }
    }
#pragma unroll
    for (int c = 0; c < 5; ++c)
        for (int off = 32; off > 0; off >>= 1)
            acc[c] += __shfl_xor(acc[c], off);
    if (lane == 0) {
#pragma unroll
        for (int c = 0; c < 5; ++c)
            proj[(size_t)row * 8 + c] = acc[c];
    }
}

// ---------------------------------------------------------------------------
// transpose V: tv[b*T + j][h*DH + d]  ->  vt[(b*8+h)*DH + d][j]
// ---------------------------------------------------------------------------
__global__ __launch_bounds__(256) void transpose_v_k(
    const bf16* __restrict__ tv, bf16* __restrict__ vt)
{
    __shared__ short Tsh[64 * 72];
    const int j0 = blockIdx.x * 64, d0 = blockIdx.y * 64, b = blockIdx.z;
    const int tid = threadIdx.x;
#pragma unroll
    for (int i = 0; i < 2; ++i) {
        const int c = tid + i * 256;
        const int r = c >> 3, kc = (c & 7) * 8;
        short8 v = *(const short8*)(tv + (size_t)(b * Tsz + j0 + r) * Dsz + d0 + kc);
#pragma unroll
        for (int q = 0; q < 8; ++q)
            Tsh[(kc + q) * 72 + r] = v[q];   // Tsh[d][j]
    }
    __syncthreads();
    const int h = d0 >> 7, dbase = d0 & 127;
#pragma unroll
    for (int i = 0; i < 2; ++i) {
        const int c = tid + i * 256;
        const int dr = c >> 3, jc = (c & 7) * 8;
        short8 o = *(const short8*)(Tsh + dr * 72 + jc);
        *(short8*)(vt + ((size_t)(b * Hn + h) * DH + dbase + dr) * Tsz + j0 + jc) = o;
    }
}

// ---------------------------------------------------------------------------
// Flash-style fused attention core (no max subtraction; logits are small):
//   per (bh, 128-row Q-tile): loop K-tiles:
//     S^T = mfma(K, Q)  [lane holds i=fr col, j=(g*4+r) rows]
//     p = exp((S + relpos_bias)*SCALE); rowsum accumulate
//     P -> LDS (bf16, packed b64 writes, XOR-swizzled)
//     ctx_acc += mfma(P, V^T)
//   writes ctx (bf16) and 1/rowsum (for weights_k). No S*S global traffic.
// ---------------------------------------------------------------------------
__global__ __launch_bounds__(256) void flash_pv_k(
    const bf16* __restrict__ tq, const bf16* __restrict__ tk,
    const bf16* __restrict__ vt, const float* __restrict__ proj,
    float* __restrict__ invs_g, bf16* __restrict__ ctx)
{
    __shared__ __align__(16) bf16 Qs[128 * LDK];
    __shared__ __align__(16) bf16 Ks[128 * LDK];
    __shared__ __align__(16) bf16 Vs[128 * LDK];
    __shared__ __align__(16) bf16 Ps[128 * 128];   // XOR-swizzled
    __shared__ float proj_s[5 * 132];
    __shared__ float sums_l[2 * 128];
    __shared__ float inv_t[128];

    const int tid = threadIdx.x;
    const int qt = blockIdx.x, z = blockIdx.y;
    const int b = z >> 3, h = z & 7;
    const int i0 = qt * 128;
    const int lane = tid & 63, w = tid >> 6;
    const int wA = w >> 1;   // j-half (S^T A) / i-half (PV A)
    const int wB = w & 1;    // i-half (S^T B) / d-half (PV B)
    const int fr = lane & 15, g = lane >> 4;
    const int sr = tid >> 1, sc = (tid & 1) * 64;

    // stage Q tile (persistent) + proj rows
    {
        const bf16* qg = tq + (size_t)(b * Tsz + i0 + sr) * Dsz + h * DH + sc;
#pragma unroll
        for (int q = 0; q < 8; ++q)
            *(short8*)(Qs + sr * LDK + sc + q * 8) = *(const short8*)(qg + q * 8);
        if (tid < 128) {
            const float* pr = proj + (size_t)(b * Tsz + i0 + tid) * 8;
#pragma unroll
            for (int c = 0; c < 5; ++c) proj_s[c * 132 + tid] = pr[c];
        }
    }

    f32x4 accp[4][4];
    const f32x4 vz = {0.f, 0.f, 0.f, 0.f};
#pragma unroll
    for (int m = 0; m < 4; ++m)
#pragma unroll
        for (int n = 0; n < 4; ++n) accp[m][n] = vz;
    float rs[4] = {0.f, 0.f, 0.f, 0.f};

#pragma unroll 1
    for (int kt = 0; kt < Tsz / 128; ++kt) {
        const int j0 = kt * 128;
        __syncthreads();   // prev ktile's Ks/Vs/Ps reads done
        {
            const bf16* kg = tk + (size_t)(b * Tsz + j0 + sr) * Dsz + h * DH + sc;
            const bf16* vg = vt + ((size_t)z * DH + sr) * Tsz + j0 + sc;
            short8 kv[8], vv[8];
#pragma unroll
            for (int q = 0; q < 8; ++q) kv[q] = *(const short8*)(kg + q * 8);
#pragma unroll
            for (int q = 0; q < 8; ++q) vv[q] = *(const short8*)(vg + q * 8);
#pragma unroll
            for (int q = 0; q < 8; ++q) *(short8*)(Ks + sr * LDK + sc + q * 8) = kv[q];
#pragma unroll
            for (int q = 0; q < 8; ++q) *(short8*)(Vs + sr * LDK + sc + q * 8) = vv[q];
        }
        __syncthreads();

        // S^T = K x Q^T : acc[mj][ni], j = wA*64+mj*16+g*4+r, i = wB*64+ni*16+fr
        f32x4 as[4][4];
#pragma unroll
        for (int m = 0; m < 4; ++m)
#pragma unroll
            for (int n = 0; n < 4; ++n) as[m][n] = vz;
#pragma unroll
        for (int ks = 0; ks < 4; ++ks) {
            short8 af[4], bfv[4];
#pragma unroll
            for (int mj = 0; mj < 4; ++mj)
                af[mj] = *(const short8*)(Ks + (wA * 64 + mj * 16 + fr) * LDK + ks * 32 + g * 8);
#pragma unroll
            for (int ni = 0; ni < 4; ++ni)
                bfv[ni] = *(const short8*)(Qs + (wB * 64 + ni * 16 + fr) * LDK + ks * 32 + g * 8);
#pragma unroll
            for (int mj = 0; mj < 4; ++mj)
#pragma unroll
                for (int ni = 0; ni < 4; ++ni)
                    as[mj][ni] = __builtin_amdgcn_mfma_f32_16x16x32_bf16(
                        af[mj], bfv[ni], as[mj][ni], 0, 0, 0);
        }

        // bias + exp + rowsum + pack P -> LDS (swizzled)
        const int dt = kt - qt;
        if (dt <= -2 || dt >= 2) {
            const int c = (dt >= 2) ? 4 : 0;
#pragma unroll
            for (int ni = 0; ni < 4; ++ni) {
                const int il = wB * 64 + ni * 16 + fr;
                const float bias = proj_s[c * 132 + il];
#pragma unroll
                for (int mj = 0; mj < 4; ++mj) {
                    const int jl0 = wA * 64 + mj * 16 + g * 4;
                    short4v pk;
#pragma unroll
                    for (int r = 0; r < 4; ++r) {
                        float p = __expf((as[mj][ni][r] + bias) * SCALE);
                        rs[ni] += p;
                        pk[r] = (short)f2bf(p);
                    }
                    const int off = ((il * 128 + jl0) * 2) ^ ((il & 7) << 4);
                    *(short4v*)((char*)Ps + off) = pk;
                }
            }
        } else {
#pragma unroll
            for (int ni = 0; ni < 4; ++ni) {
                const int il = wB * 64 + ni * 16 + fr;
#pragma unroll
                for (int mj = 0; mj < 4; ++mj) {
                    const int jl0 = wA * 64 + mj * 16 + g * 4;
                    short4v pk;
#pragma unroll
                    for (int r = 0; r < 4; ++r) {
                        int dd = (jl0 + r + dt * 128) - il;
                        dd = dd < -2 ? -2 : (dd > 2 ? 2 : dd);
                        const float bias = proj_s[(dd + 2) * 132 + il];
                        float p = __expf((as[mj][ni][r] + bias) * SCALE);
                        rs[ni] += p;
                        pk[r] = (short)f2bf(p);
                    }
                    const int off = ((il * 128 + jl0) * 2) ^ ((il & 7) << 4);
                    *(short4v*)((char*)Ps + off) = pk;
                }
            }
        }
        __syncthreads();   // P visible to all waves

        // PV: ctx_acc += P x V^T : i = wA*64+m2*16+..., d = wB*64+n2*16+fr
#pragma unroll
        for (int ks = 0; ks < 4; ++ks) {
            short8 af[4], bfv[4];
#pragma unroll
            for (int m2 = 0; m2 < 4; ++m2) {
                const int il2 = wA * 64 + m2 * 16 + fr;
                const int off = ((il2 * 128 + ks * 32 + g * 8) * 2) ^ ((il2 & 7) << 4);
                af[m2] = *(const short8*)((char*)Ps + off);
            }
#pragma unroll
            for (int n2 = 0; n2 < 4; ++n2)
                bfv[n2] = *(const short8*)(Vs + (wB * 64 + n2 * 16 + fr) * LDK + ks * 32 + g * 8);
#pragma unroll
            for (int m2 = 0; m2 < 4; ++m2)
#pragma unroll
                for (int n2 = 0; n2 < 4; ++n2)
                    accp[m2][n2] = __builtin_amdgcn_mfma_f32_16x16x32_bf16(
                        af[m2], bfv[n2], accp[m2][n2], 0, 0, 0);
        }
    }

    // row-sum reduction: over g (lane bits 4,5), then across j-half waves
#pragma unroll
    for (int ni = 0; ni < 4; ++ni) {
        rs[ni] += __shfl_xor(rs[ni], 16);
        rs[ni] += __shfl_xor(rs[ni], 32);
    }
    if (lane < 16) {
#pragma unroll
        for (int ni = 0; ni < 4; ++ni)
            sums_l[wA * 128 + wB * 64 + ni * 16 + fr] = rs[ni];
    }
    __syncthreads();
    if (tid < 128) {
        const float tot = sums_l[tid] + sums_l[128 + tid];
        const float iv = 1.0f / tot;
        inv_t[tid] = iv;
        invs_g[(size_t)z * Tsz + i0 + tid] = iv;
    }
    __syncthreads();

    // ctx epilogue
    bf16* cp = ctx + (size_t)(b * Tsz + i0) * Dsz + h * DH;
#pragma unroll
    for (int m2 = 0; m2 < 4; ++m2) {
#pragma unroll
        for (int r = 0; r < 4; ++r) {
            const int il = wA * 64 + m2 * 16 + g * 4 + r;
            const float iv = inv_t[il];
#pragma unroll
            for (int n2 = 0; n2 < 4; ++n2) {
                const int d = wB * 64 + n2 * 16 + fr;
                cp[(size_t)il * Dsz + d] = __float2bfloat16(accp[m2][n2][r] * iv);
            }
        }
    }
}

// ---------------------------------------------------------------------------
// weights: Wt[z,i,j] = exp((q·k + relpos)*SCALE) * invs[z,i]   (fp32 write)
// ---------------------------------------------------------------------------
__global__ __launch_bounds__(256) void weights_k(
    const bf16* __restrict__ tq, const bf16* __restrict__ tk,
    const float* __restrict__ proj, const float* __restrict__ invs_g,
    float* __restrict__ Wt)
{
    __shared__ __align__(16) bf16 As[128 * LDT];
    __shared__ __align__(16) bf16 Bs[128 * LDT];
    const int tid = threadIdx.x;
    const int z = blockIdx.z, b = z >> 3, h = z & 7;
    const int row0 = blockIdx.y * 128;
    const int col0 = blockIdx.x * 128;
    const int lane = tid & 63;
    const int w = tid >> 6, wr = w >> 1, wc = w & 1;
    const int fr = lane & 15, g = lane >> 4;

    const bf16* A = tq + (size_t)b * Tsz * Dsz + h * DH;
    const bf16* B = tk + (size_t)b * Tsz * Dsz + h * DH;

    const int c0 = tid, c1 = tid + 256;
    const int r0 = c0 >> 2, kc0 = (c0 & 3) * 8;
    const int r1 = c1 >> 2, kc1 = (c1 & 3) * 8;
    const bf16* Ag0 = A + (size_t)(row0 + r0) * Dsz + kc0;
    const bf16* Ag1 = A + (size_t)(row0 + r1) * Dsz + kc1;
    const bf16* Bg0 = B + (size_t)(col0 + r0) * Dsz + kc0;
    const bf16* Bg1 = B + (size_t)(col0 + r1) * Dsz + kc1;

    f32x4 acc[4][4];
    const f32x4 vz = {0.f, 0.f, 0.f, 0.f};
#pragma unroll
    for (int m = 0; m < 4; ++m)
#pragma unroll
        for (int n = 0; n < 4; ++n) acc[m][n] = vz;

    short8 va0 = *(const short8*)Ag0;
    short8 va1 = *(const short8*)Ag1;
    short8 vb0 = *(const short8*)Bg0;
    short8 vb1 = *(const short8*)Bg1;

    for (int k0 = 0; k0 < DH; k0 += 32) {
        __syncthreads();
        *(short8*)(As + r0 * LDT + kc0) = va0;
        *(short8*)(As + r1 * LDT + kc1) = va1;
        *(short8*)(Bs + r0 * LDT + kc0) = vb0;
        *(short8*)(Bs + r1 * LDT + kc1) = vb1;
        __syncthreads();
        if (k0 + 32 < DH) {
            va0 = *(const short8*)(Ag0 + k0 + 32);
            va1 = *(const short8*)(Ag1 + k0 + 32);
            vb0 = *(const short8*)(Bg0 + k0 + 32);
            vb1 = *(const short8*)(Bg1 + k0 + 32);
        }
        mfma_step(As, Bs, acc, wr, wc, fr, g);
    }

    float* C = Wt + (size_t)z * Tsz * Tsz;
#pragma unroll
    for (int m = 0; m < 4; ++m) {
#pragma unroll
        for (int r = 0; r < 4; ++r) {
            const int gi = row0 + wr * 64 + m * 16 + g * 4 + r;
            const float* prow = proj + (size_t)(b * Tsz + gi) * 8;
            const float iv = invs_g[(size_t)z * Tsz + gi];
#pragma unroll
            for (int n = 0; n < 4; ++n) {
                const int gj = col0 + wc * 64 + n * 16 + fr;
                int rel = gj - gi;
                rel = rel < -2 ? -2 : (rel > 2 ? 2 : rel);
                C[(size_t)gi * Tsz + gj] =
                    __expf((acc[m][n][r] + prow[rel + 2]) * SCALE) * iv;
            }
        }
    }
}

// ---------------------------------------------------------------------------
extern "C" void kernel_launch(void* const* d_in, const int* in_sizes, int n_in,
                              void* d_out, int out_size, void* d_ws, size_t ws_size,
                              hipStream_t stream)
{
    const float* query  = (const float*)d_in[0];
    const float* keys   = (const float*)d_in[1];
    const float* values = (const float*)d_in[2];
    const float* Wq = (const float*)d_in[3];
    const float* bq = (const float*)d_in[4];
    const float* Wk = (const float*)d_in[5];
    const float* bk = (const float*)d_in[6];
    const float* Wv = (const float*)d_in[7];
    const float* bv = (const float*)d_in[8];
    const float* Wo = (const float*)d_in[9];
    const float* bo = (const float*)d_in[10];
    const float* table = (const float*)d_in[11];

    float* out     = (float*)d_out;                      // B*T*D fp32
    float* weights = out + (size_t)Bsz * Tsz * Dsz;      // B*H*T*T fp32

    const size_t NTD = (size_t)Bsz * Tsz * Dsz;          // 4M elems
    char* wp = (char*)d_ws;
    bf16* qb  = (bf16*)(wp);                              // reused as vt
    bf16* kb  = (bf16*)(wp + 8  * 1024 * 1024);           // reused as ctx
    bf16* vb  = (bf16*)(wp + 16 * 1024 * 1024);
    bf16* tq  = (bf16*)(wp + 24 * 1024 * 1024);
    bf16* tk  = (bf16*)(wp + 32 * 1024 * 1024);
    bf16* tv  = (bf16*)(wp + 40 * 1024 * 1024);
    bf16* Wqb = (bf16*)(wp + 48 * 1024 * 1024);
    bf16* Wkb = (bf16*)(wp + 50 * 1024 * 1024);
    bf16* Wvb = (bf16*)(wp + 52 * 1024 * 1024);
    bf16* Wob = (bf16*)(wp + 54 * 1024 * 1024);
    float* proj   = (float*)(wp + 56 * 1024 * 1024);      // 4096*8 fp32
    float* invs_g = (float*)(wp + 57 * 1024 * 1024);      // 16*2048 fp32
    bf16* vt  = qb;
    bf16* ctx = kb;

    const dim3 blk(256);

    CvtArgs ca;
    ca.j[0] = { query,  qb,  (int)NTD };
    ca.j[1] = { keys,   kb,  (int)NTD };
    ca.j[2] = { values, vb,  (int)NTD };
    ca.j[3] = { Wq, Wqb, Dsz * Dsz };
    ca.j[4] = { Wk, Wkb, Dsz * Dsz };
    ca.j[5] = { Wv, Wvb, Dsz * Dsz };
    ca.j[6] = { Wo, Wob, Dsz * Dsz };
    cvt_k<<<dim3(1024, 7), blk, 0, stream>>>(ca);

    gemm_nt_k<1><<<dim3(Dsz / 128, Bsz * Tsz / 128), blk, 0, stream>>>(
        qb, Dsz, Wqb, Dsz, bq, tq, Dsz, Dsz);
    gemm_nt_k<1><<<dim3(Dsz / 128, Bsz * Tsz / 128), blk, 0, stream>>>(
        kb, Dsz, Wkb, Dsz, bk, tk, Dsz, Dsz);
    gemm_nt_k<1><<<dim3(Dsz / 128, Bsz * Tsz / 128), blk, 0, stream>>>(
        vb, Dsz, Wvb, Dsz, bv, tv, Dsz, Dsz);

    relproj_k<<<dim3(Bsz * Tsz / 4), blk, 0, stream>>>(tq, table, proj);

    // V transpose (tv dead after; vt overwrites qb which is dead)
    transpose_v_k<<<dim3(Tsz / 64, Dsz / 64, Bsz), blk, 0, stream>>>(tv, vt);

    // fused attention: ctx + row-sum inverses (no S*S traffic)
    flash_pv_k<<<dim3(Tsz / 128, Bsz * Hn), blk, 0, stream>>>(
        tq, tk, vt, proj, invs_g, ctx);

    // weights output: recompute logits, exp, normalize, single 268MB write
    weights_k<<<dim3(Tsz / 128, Tsz / 128, Bsz * Hn), blk, 0, stream>>>(
        tq, tk, proj, invs_g, weights);

    // output projection (fp32 out + bias)
    gemm_nt_k<0><<<dim3(Dsz / 128, Bsz * Tsz / 128), blk, 0, stream>>>(
        ctx, Dsz, Wob, Dsz, bo, out, Dsz, Dsz);
}

// Round 4
// 255.466 us; speedup vs baseline: 4.2674x; 1.0453x over previous
//
#include <hip/hip_runtime.h>
#include <hip/hip_bf16.h>
#include <cmath>

#define Bsz 2
#define Tsz 2048
#define Dsz 1024
#define Hn  8
#define DH  128
#define SCALE 0.08838834764831845f  // 1/sqrt(128)

typedef __attribute__((ext_vector_type(8))) short short8;
typedef __attribute__((ext_vector_type(4))) short short4v;
typedef __attribute__((ext_vector_type(4))) float f32x4;
typedef __hip_bfloat16 bf16;

#define LDT 40   // padded LDS row stride (weights_k)
#define LDK 136  // flash LDS row stride (128 + 8 pad)

__device__ __forceinline__ float bf2f(unsigned short u) {
    return __uint_as_float(((unsigned)u) << 16);
}
__device__ __forceinline__ unsigned short f2bf(float f) {
    bf16 h = __float2bfloat16(f);
    return *(unsigned short*)&h;
}

// async global->LDS, 16B per lane; lds dest = wave-uniform base + lane*16
__device__ __forceinline__ void gload16(const bf16* g, bf16* l) {
    __builtin_amdgcn_global_load_lds(
        (const __attribute__((address_space(1))) void*)g,
        (__attribute__((address_space(3))) void*)l, 16, 0, 0);
}

// ---------------------------------------------------------------------------
// fp32 -> bf16 conversion, 7 tensors in one launch (blockIdx.y = job)
// ---------------------------------------------------------------------------
struct CvtJob { const float* s; bf16* d; int n; };
struct CvtArgs { CvtJob j[7]; };

__global__ __launch_bounds__(256) void cvt_k(CvtArgs a) {
    CvtJob job = a.j[blockIdx.y];
    int idx = (blockIdx.x * 256 + threadIdx.x) * 8;
    const int stride = gridDim.x * 256 * 8;
    for (; idx < job.n; idx += stride) {
        float4 f0 = *(const float4*)(job.s + idx);
        float4 f1 = *(const float4*)(job.s + idx + 4);
        short8 o;
        o[0] = (short)f2bf(f0.x); o[1] = (short)f2bf(f0.y);
        o[2] = (short)f2bf(f0.z); o[3] = (short)f2bf(f0.w);
        o[4] = (short)f2bf(f1.x); o[5] = (short)f2bf(f1.y);
        o[6] = (short)f2bf(f1.z); o[7] = (short)f2bf(f1.w);
        *(short8*)(job.d + idx) = o;
    }
}

// ---------------------------------------------------------------------------
// MFMA step over linear [128][32] LDS tiles (global_load_lds staged)
// ---------------------------------------------------------------------------
__device__ __forceinline__ void mfma_step32(const bf16* As, const bf16* Bs,
                                            f32x4 acc[4][4],
                                            int wr, int wc, int fr, int g)
{
    short8 af[4], bfv[4];
#pragma unroll
    for (int m = 0; m < 4; ++m)
        af[m] = *(const short8*)(As + (wr * 64 + m * 16 + fr) * 32 + g * 8);
#pragma unroll
    for (int n = 0; n < 4; ++n)
        bfv[n] = *(const short8*)(Bs + (wc * 64 + n * 16 + fr) * 32 + g * 8);
#pragma unroll
    for (int m = 0; m < 4; ++m)
#pragma unroll
        for (int n = 0; n < 4; ++n)
            acc[m][n] = __builtin_amdgcn_mfma_f32_16x16x32_bf16(
                af[m], bfv[n], acc[m][n], 0, 0, 0);
}

// ---------------------------------------------------------------------------
// Multi-job NT GEMM, K = lda = ldb = 1024.  C[M][N] = A@B^T + bias.
// mode 0: fp32 C (ldc=1024); mode 1: bf16 C (ldc=1024);
// mode 2: bf16 transposed V-layout write  vt[(b*8+h)*128+d][j]
// blockIdx.z picks the job. global_load_lds staging, 2-barrier loop.
// ---------------------------------------------------------------------------
struct GemmJob { const bf16* A; const bf16* B; const float* bias; void* C; int mode; };
struct GemmArgs { GemmJob j[3]; };

__global__ __launch_bounds__(256, 3) void gemm_multi_k(GemmArgs args)
{
    __shared__ __align__(16) bf16 As[128 * 32];
    __shared__ __align__(16) bf16 Bs[128 * 32];
    const GemmJob job = args.j[blockIdx.z];
    const int tid = threadIdx.x;
    const int row0 = blockIdx.y * 128;
    const int col0 = blockIdx.x * 128;
    const int lane = tid & 63;
    const int w = tid >> 6, wr = w >> 1, wc = w & 1;
    const int fr = lane & 15, g = lane >> 4;

    const int srow = lane >> 2, scol = (lane & 3) * 8;
    const bf16* Ag = job.A + (size_t)(row0 + w * 32 + srow) * Dsz + scol;
    const bf16* Bg = job.B + (size_t)(col0 + w * 32 + srow) * Dsz + scol;
    const int lofs = __builtin_amdgcn_readfirstlane(w * 32 * 32);
    bf16* Asw = As + lofs;
    bf16* Bsw = Bs + lofs;

    f32x4 acc[4][4];
    const f32x4 vz = {0.f, 0.f, 0.f, 0.f};
#pragma unroll
    for (int m = 0; m < 4; ++m)
#pragma unroll
        for (int n = 0; n < 4; ++n) acc[m][n] = vz;

#pragma unroll 1
    for (int k0 = 0; k0 < Dsz; k0 += 32) {
        gload16(Ag + k0, Asw);
        gload16(Ag + 16 * Dsz + k0, Asw + 16 * 32);
        gload16(Bg + k0, Bsw);
        gload16(Bg + 16 * Dsz + k0, Bsw + 16 * 32);
        __syncthreads();   // drains vmcnt -> staged data visible
        mfma_step32(As, Bs, acc, wr, wc, fr, g);
        __syncthreads();   // all reads done before next stage overwrites
    }

    if (job.mode == 2) {
        // transposed V write: vt[((gi>>11)*8 + gj>>7)*128 + (gj&127)][gi&2047]
        bf16* vtp = (bf16*)job.C;
#pragma unroll
        for (int m = 0; m < 4; ++m) {
            const int gi0 = row0 + wr * 64 + m * 16 + g * 4;
            const int bidx = gi0 >> 11, jj = gi0 & 2047;
#pragma unroll
            for (int n = 0; n < 4; ++n) {
                const int gj = col0 + wc * 64 + n * 16 + fr;
                const float bv = job.bias[gj];
                short4v pk;
#pragma unroll
                for (int r = 0; r < 4; ++r)
                    pk[r] = (short)f2bf(acc[m][n][r] + bv);
                const size_t zrow = ((size_t)bidx * 8 + (gj >> 7)) * 128 + (gj & 127);
                *(short4v*)(vtp + zrow * Tsz + jj) = pk;
            }
        }
    } else {
#pragma unroll
        for (int m = 0; m < 4; ++m) {
#pragma unroll
            for (int r = 0; r < 4; ++r) {
                const int gi = row0 + wr * 64 + m * 16 + g * 4 + r;
#pragma unroll
                for (int n = 0; n < 4; ++n) {
                    const int gj = col0 + wc * 64 + n * 16 + fr;
                    float x = acc[m][n][r] + job.bias[gj];
                    if (job.mode == 1)
                        ((bf16*)job.C)[(size_t)gi * Dsz + gj] = __float2bfloat16(x);
                    else
                        ((float*)job.C)[(size_t)gi * Dsz + gj] = x;
                }
            }
        }
    }
}

// ---------------------------------------------------------------------------
// relpos projection: proj[row][c] = dot(tq[row], table[c]), c in 0..4
// ---------------------------------------------------------------------------
__global__ __launch_bounds__(256) void relproj_k(
    const bf16* __restrict__ tq, const float* __restrict__ table,
    float* __restrict__ proj)
{
    const int row  = blockIdx.x * 4 + (threadIdx.x >> 6);
    const int lane = threadIdx.x & 63;
    const bf16* qrow = tq + (size_t)row * Dsz;
    float acc[5] = {0.f, 0.f, 0.f, 0.f, 0.f};
#pragma unroll
    for (int t = 0; t < 4; ++t) {
        const int d = t * 256 + lane * 4;
        short4v q4 = *(const short4v*)(qrow + d);
        float qv[4];
#pragma unroll
        for (int q = 0; q < 4; ++q) qv[q] = bf2f((unsigned short)q4[q]);
#pragma unroll
        for (int c = 0; c < 5; ++c) {
            float4 t4 = *(const float4*)(table + c * Dsz + d);
            acc[c] = fmaf(qv[0], t4.x, acc[c]);
            acc[c] = fmaf(qv[1], t4.y, acc[c]);
            acc[c] = fmaf(qv[2], t4.z, acc[c]);
            acc[c] = fmaf(qv[3], t4.w, acc[c]);
        }
    }
#pragma unroll
    for (int c = 0; c < 5; ++c)
        for (int off = 32; off > 0; off >>= 1)
            acc[c] += __shfl_xor(acc[c], off);
    if (lane == 0) {
#pragma unroll
        for (int c = 0; c < 5; ++c)
            proj[(size_t)row * 8 + c] = acc[c];
    }
}

// ---------------------------------------------------------------------------
// Flash-style fused attention core (no max subtraction; logits are small)
// ---------------------------------------------------------------------------
__global__ __launch_bounds__(256) void flash_pv_k(
    const bf16* __restrict__ tq, const bf16* __restrict__ tk,
    const bf16* __restrict__ vt, const float* __restrict__ proj,
    float* __restrict__ invs_g, bf16* __restrict__ ctx)
{
    __shared__ __align__(16) bf16 Qs[128 * LDK];
    __shared__ __align__(16) bf16 Ks[128 * LDK];
    __shared__ __align__(16) bf16 Vs[128 * LDK];
    __shared__ __align__(16) bf16 Ps[128 * 128];   // XOR-swizzled
    __shared__ float proj_s[5 * 132];
    __shared__ float sums_l[2 * 128];
    __shared__ float inv_t[128];

    const int tid = threadIdx.x;
    const int qt = blockIdx.x, z = blockIdx.y;
    const int b = z >> 3, h = z & 7;
    const int i0 = qt * 128;
    const int lane = tid & 63, w = tid >> 6;
    const int wA = w >> 1;
    const int wB = w & 1;
    const int fr = lane & 15, g = lane >> 4;
    const int sr = tid >> 1, sc = (tid & 1) * 64;

    {
        const bf16* qg = tq + (size_t)(b * Tsz + i0 + sr) * Dsz + h * DH + sc;
#pragma unroll
        for (int q = 0; q < 8; ++q)
            *(short8*)(Qs + sr * LDK + sc + q * 8) = *(const short8*)(qg + q * 8);
        if (tid < 128) {
            const float* pr = proj + (size_t)(b * Tsz + i0 + tid) * 8;
#pragma unroll
            for (int c = 0; c < 5; ++c) proj_s[c * 132 + tid] = pr[c];
        }
    }

    f32x4 accp[4][4];
    const f32x4 vz = {0.f, 0.f, 0.f, 0.f};
#pragma unroll
    for (int m = 0; m < 4; ++m)
#pragma unroll
        for (int n = 0; n < 4; ++n) accp[m][n] = vz;
    float rs[4] = {0.f, 0.f, 0.f, 0.f};

#pragma unroll 1
    for (int kt = 0; kt < Tsz / 128; ++kt) {
        const int j0 = kt * 128;
        __syncthreads();
        {
            const bf16* kg = tk + (size_t)(b * Tsz + j0 + sr) * Dsz + h * DH + sc;
            const bf16* vg = vt + ((size_t)z * DH + sr) * Tsz + j0 + sc;
            short8 kv[8], vv[8];
#pragma unroll
            for (int q = 0; q < 8; ++q) kv[q] = *(const short8*)(kg + q * 8);
#pragma unroll
            for (int q = 0; q < 8; ++q) vv[q] = *(const short8*)(vg + q * 8);
#pragma unroll
            for (int q = 0; q < 8; ++q) *(short8*)(Ks + sr * LDK + sc + q * 8) = kv[q];
#pragma unroll
            for (int q = 0; q < 8; ++q) *(short8*)(Vs + sr * LDK + sc + q * 8) = vv[q];
        }
        __syncthreads();

        // S^T = K x Q^T
        f32x4 as[4][4];
#pragma unroll
        for (int m = 0; m < 4; ++m)
#pragma unroll
            for (int n = 0; n < 4; ++n) as[m][n] = vz;
#pragma unroll
        for (int ks = 0; ks < 4; ++ks) {
            short8 af[4], bfv[4];
#pragma unroll
            for (int mj = 0; mj < 4; ++mj)
                af[mj] = *(const short8*)(Ks + (wA * 64 + mj * 16 + fr) * LDK + ks * 32 + g * 8);
#pragma unroll
            for (int ni = 0; ni < 4; ++ni)
                bfv[ni] = *(const short8*)(Qs + (wB * 64 + ni * 16 + fr) * LDK + ks * 32 + g * 8);
#pragma unroll
            for (int mj = 0; mj < 4; ++mj)
#pragma unroll
                for (int ni = 0; ni < 4; ++ni)
                    as[mj][ni] = __builtin_amdgcn_mfma_f32_16x16x32_bf16(
                        af[mj], bfv[ni], as[mj][ni], 0, 0, 0);
        }

        const int dt = kt - qt;
        if (dt <= -2 || dt >= 2) {
            const int c = (dt >= 2) ? 4 : 0;
#pragma unroll
            for (int ni = 0; ni < 4; ++ni) {
                const int il = wB * 64 + ni * 16 + fr;
                const float bias = proj_s[c * 132 + il];
#pragma unroll
                for (int mj = 0; mj < 4; ++mj) {
                    const int jl0 = wA * 64 + mj * 16 + g * 4;
                    short4v pk;
#pragma unroll
                    for (int r = 0; r < 4; ++r) {
                        float p = __expf((as[mj][ni][r] + bias) * SCALE);
                        rs[ni] += p;
                        pk[r] = (short)f2bf(p);
                    }
                    const int off = ((il * 128 + jl0) * 2) ^ ((il & 7) << 4);
                    *(short4v*)((char*)Ps + off) = pk;
                }
            }
        } else {
#pragma unroll
            for (int ni = 0; ni < 4; ++ni) {
                const int il = wB * 64 + ni * 16 + fr;
#pragma unroll
                for (int mj = 0; mj < 4; ++mj) {
                    const int jl0 = wA * 64 + mj * 16 + g * 4;
                    short4v pk;
#pragma unroll
                    for (int r = 0; r < 4; ++r) {
                        int dd = (jl0 + r + dt * 128) - il;
                        dd = dd < -2 ? -2 : (dd > 2 ? 2 : dd);
                        const float bias = proj_s[(dd + 2) * 132 + il];
                        float p = __expf((as[mj][ni][r] + bias) * SCALE);
                        rs[ni] += p;
                        pk[r] = (short)f2bf(p);
                    }
                    const int off = ((il * 128 + jl0) * 2) ^ ((il & 7) << 4);
                    *(short4v*)((char*)Ps + off) = pk;
                }
            }
        }
        __syncthreads();

        // PV
#pragma unroll
        for (int ks = 0; ks < 4; ++ks) {
            short8 af[4], bfv[4];
#pragma unroll
            for (int m2 = 0; m2 < 4; ++m2) {
                const int il2 = wA * 64 + m2 * 16 + fr;
                const int off = ((il2 * 128 + ks * 32 + g * 8) * 2) ^ ((il2 & 7) << 4);
                af[m2] = *(const short8*)((char*)Ps + off);
            }
#pragma unroll
            for (int n2 = 0; n2 < 4; ++n2)
                bfv[n2] = *(const short8*)(Vs + (wB * 64 + n2 * 16 + fr) * LDK + ks * 32 + g * 8);
#pragma unroll
            for (int m2 = 0; m2 < 4; ++m2)
#pragma unroll
                for (int n2 = 0; n2 < 4; ++n2)
                    accp[m2][n2] = __builtin_amdgcn_mfma_f32_16x16x32_bf16(
                        af[m2], bfv[n2], accp[m2][n2], 0, 0, 0);
        }
    }

#pragma unroll
    for (int ni = 0; ni < 4; ++ni) {
        rs[ni] += __shfl_xor(rs[ni], 16);
        rs[ni] += __shfl_xor(rs[ni], 32);
    }
    if (lane < 16) {
#pragma unroll
        for (int ni = 0; ni < 4; ++ni)
            sums_l[wA * 128 + wB * 64 + ni * 16 + fr] = rs[ni];
    }
    __syncthreads();
    if (tid < 128) {
        const float tot = sums_l[tid] + sums_l[128 + tid];
        const float iv = 1.0f / tot;
        inv_t[tid] = iv;
        invs_g[(size_t)z * Tsz + i0 + tid] = iv;
    }
    __syncthreads();

    bf16* cp = ctx + (size_t)(b * Tsz + i0) * Dsz + h * DH;
#pragma unroll
    for (int m2 = 0; m2 < 4; ++m2) {
#pragma unroll
        for (int r = 0; r < 4; ++r) {
            const int il = wA * 64 + m2 * 16 + g * 4 + r;
            const float iv = inv_t[il];
#pragma unroll
            for (int n2 = 0; n2 < 4; ++n2) {
                const int d = wB * 64 + n2 * 16 + fr;
                cp[(size_t)il * Dsz + d] = __float2bfloat16(accp[m2][n2][r] * iv);
            }
        }
    }
}

// ---------------------------------------------------------------------------
// weights: Wt[z,i,j] = exp((q·k + relpos)*SCALE) * invs[z,i]   (fp32 write)
// ---------------------------------------------------------------------------
__global__ __launch_bounds__(256) void weights_k(
    const bf16* __restrict__ tq, const bf16* __restrict__ tk,
    const float* __restrict__ proj, const float* __restrict__ invs_g,
    float* __restrict__ Wt)
{
    __shared__ __align__(16) bf16 As[128 * LDT];
    __shared__ __align__(16) bf16 Bs[128 * LDT];
    const int tid = threadIdx.x;
    const int z = blockIdx.z, b = z >> 3, h = z & 7;
    const int row0 = blockIdx.y * 128;
    const int col0 = blockIdx.x * 128;
    const int lane = tid & 63;
    const int w = tid >> 6, wr = w >> 1, wc = w & 1;
    const int fr = lane & 15, g = lane >> 4;

    const bf16* A = tq + (size_t)b * Tsz * Dsz + h * DH;
    const bf16* B = tk + (size_t)b * Tsz * Dsz + h * DH;

    const int c0 = tid, c1 = tid + 256;
    const int r0 = c0 >> 2, kc0 = (c0 & 3) * 8;
    const int r1 = c1 >> 2, kc1 = (c1 & 3) * 8;
    const bf16* Ag0 = A + (size_t)(row0 + r0) * Dsz + kc0;
    const bf16* Ag1 = A + (size_t)(row0 + r1) * Dsz + kc1;
    const bf16* Bg0 = B + (size_t)(col0 + r0) * Dsz + kc0;
    const bf16* Bg1 = B + (size_t)(col0 + r1) * Dsz + kc1;

    f32x4 acc[4][4];
    const f32x4 vz = {0.f, 0.f, 0.f, 0.f};
#pragma unroll
    for (int m = 0; m < 4; ++m)
#pragma unroll
        for (int n = 0; n < 4; ++n) acc[m][n] = vz;

    short8 va0 = *(const short8*)Ag0;
    short8 va1 = *(const short8*)Ag1;
    short8 vb0 = *(const short8*)Bg0;
    short8 vb1 = *(const short8*)Bg1;

    for (int k0 = 0; k0 < DH; k0 += 32) {
        __syncthreads();
        *(short8*)(As + r0 * LDT + kc0) = va0;
        *(short8*)(As + r1 * LDT + kc1) = va1;
        *(short8*)(Bs + r0 * LDT + kc0) = vb0;
        *(short8*)(Bs + r1 * LDT + kc1) = vb1;
        __syncthreads();
        if (k0 + 32 < DH) {
            va0 = *(const short8*)(Ag0 + k0 + 32);
            va1 = *(const short8*)(Ag1 + k0 + 32);
            vb0 = *(const short8*)(Bg0 + k0 + 32);
            vb1 = *(const short8*)(Bg1 + k0 + 32);
        }
        {
            short8 af[4], bfv[4];
#pragma unroll
            for (int m = 0; m < 4; ++m)
                af[m] = *(const short8*)(As + (wr * 64 + m * 16 + fr) * LDT + g * 8);
#pragma unroll
            for (int n = 0; n < 4; ++n)
                bfv[n] = *(const short8*)(Bs + (wc * 64 + n * 16 + fr) * LDT + g * 8);
#pragma unroll
            for (int m = 0; m < 4; ++m)
#pragma unroll
                for (int n = 0; n < 4; ++n)
                    acc[m][n] = __builtin_amdgcn_mfma_f32_16x16x32_bf16(
                        af[m], bfv[n], acc[m][n], 0, 0, 0);
        }
    }

    float* C = Wt + (size_t)z * Tsz * Tsz;
#pragma unroll
    for (int m = 0; m < 4; ++m) {
#pragma unroll
        for (int r = 0; r < 4; ++r) {
            const int gi = row0 + wr * 64 + m * 16 + g * 4 + r;
            const float* prow = proj + (size_t)(b * Tsz + gi) * 8;
            const float iv = invs_g[(size_t)z * Tsz + gi];
#pragma unroll
            for (int n = 0; n < 4; ++n) {
                const int gj = col0 + wc * 64 + n * 16 + fr;
                int rel = gj - gi;
                rel = rel < -2 ? -2 : (rel > 2 ? 2 : rel);
                C[(size_t)gi * Tsz + gj] =
                    __expf((acc[m][n][r] + prow[rel + 2]) * SCALE) * iv;
            }
        }
    }
}

// ---------------------------------------------------------------------------
extern "C" void kernel_launch(void* const* d_in, const int* in_sizes, int n_in,
                              void* d_out, int out_size, void* d_ws, size_t ws_size,
                              hipStream_t stream)
{
    const float* query  = (const float*)d_in[0];
    const float* keys   = (const float*)d_in[1];
    const float* values = (const float*)d_in[2];
    const float* Wq = (const float*)d_in[3];
    const float* bq = (const float*)d_in[4];
    const float* Wk = (const float*)d_in[5];
    const float* bk = (const float*)d_in[6];
    const float* Wv = (const float*)d_in[7];
    const float* bv = (const float*)d_in[8];
    const float* Wo = (const float*)d_in[9];
    const float* bo = (const float*)d_in[10];
    const float* table = (const float*)d_in[11];

    float* out     = (float*)d_out;                      // B*T*D fp32
    float* weights = out + (size_t)Bsz * Tsz * Dsz;      // B*H*T*T fp32

    const size_t NTD = (size_t)Bsz * Tsz * Dsz;          // 4M elems
    char* wp = (char*)d_ws;
    bf16* qb  = (bf16*)(wp);
    bf16* kb  = (bf16*)(wp + 8  * 1024 * 1024);          // reused as ctx
    bf16* vb  = (bf16*)(wp + 16 * 1024 * 1024);
    bf16* tq  = (bf16*)(wp + 24 * 1024 * 1024);
    bf16* tk  = (bf16*)(wp + 32 * 1024 * 1024);
    bf16* vt  = (bf16*)(wp + 40 * 1024 * 1024);          // V in [z][d][j] layout
    bf16* Wqb = (bf16*)(wp + 48 * 1024 * 1024);
    bf16* Wkb = (bf16*)(wp + 50 * 1024 * 1024);
    bf16* Wvb = (bf16*)(wp + 52 * 1024 * 1024);
    bf16* Wob = (bf16*)(wp + 54 * 1024 * 1024);
    float* proj   = (float*)(wp + 56 * 1024 * 1024);
    float* invs_g = (float*)(wp + 57 * 1024 * 1024);
    bf16* ctx = kb;

    const dim3 blk(256);

    CvtArgs ca;
    ca.j[0] = { query,  qb,  (int)NTD };
    ca.j[1] = { keys,   kb,  (int)NTD };
    ca.j[2] = { values, vb,  (int)NTD };
    ca.j[3] = { Wq, Wqb, Dsz * Dsz };
    ca.j[4] = { Wk, Wkb, Dsz * Dsz };
    ca.j[5] = { Wv, Wvb, Dsz * Dsz };
    ca.j[6] = { Wo, Wob, Dsz * Dsz };
    cvt_k<<<dim3(1024, 7), blk, 0, stream>>>(ca);

    // fused Q/K/V projections; V written directly in transposed [z][d][j] form
    GemmArgs ga;
    ga.j[0] = { qb, Wqb, bq, tq, 1 };
    ga.j[1] = { kb, Wkb, bk, tk, 1 };
    ga.j[2] = { vb, Wvb, bv, vt, 2 };
    gemm_multi_k<<<dim3(Dsz / 128, Bsz * Tsz / 128, 3), blk, 0, stream>>>(ga);

    relproj_k<<<dim3(Bsz * Tsz / 4), blk, 0, stream>>>(tq, table, proj);

    // fused attention: ctx + row-sum inverses (no S*S traffic)
    flash_pv_k<<<dim3(Tsz / 128, Bsz * Hn), blk, 0, stream>>>(
        tq, tk, vt, proj, invs_g, ctx);

    // weights output: recompute logits, exp, normalize, single 268MB write
    weights_k<<<dim3(Tsz / 128, Tsz / 128, Bsz * Hn), blk, 0, stream>>>(
        tq, tk, proj, invs_g, weights);

    // output projection (fp32 out + bias)
    GemmArgs go;
    go.j[0] = { ctx, Wob, bo, out, 0 };
    go.j[1] = go.j[0]; go.j[2] = go.j[0];
    gemm_multi_k<<<dim3(Dsz / 128, Bsz * Tsz / 128, 1), blk, 0, stream>>>(go);
}

// Round 5
// 246.496 us; speedup vs baseline: 4.4227x; 1.0364x over previous
//
#include <hip/hip_runtime.h>
#include <hip/hip_bf16.h>
#include <cmath>

#define Bsz 2
#define Tsz 2048
#define Dsz 1024
#define Hn  8
#define DH  128
#define SCALE 0.08838834764831845f  // 1/sqrt(128)

typedef __attribute__((ext_vector_type(8))) short short8;
typedef __attribute__((ext_vector_type(4))) short short4v;
typedef __attribute__((ext_vector_type(4))) float f32x4;
typedef __hip_bfloat16 bf16;

#define LDK 136  // flash LDS row stride (128 + 8 pad)

__device__ __forceinline__ float bf2f(unsigned short u) {
    return __uint_as_float(((unsigned)u) << 16);
}
__device__ __forceinline__ unsigned short f2bf(float f) {
    bf16 h = __float2bfloat16(f);
    return *(unsigned short*)&h;
}

// async global->LDS, 16B per lane; lds dest = wave-uniform base + lane*16
__device__ __forceinline__ void gload16(const bf16* g, bf16* l) {
    __builtin_amdgcn_global_load_lds(
        (const __attribute__((address_space(1))) void*)g,
        (__attribute__((address_space(3))) void*)l, 16, 0, 0);
}

// ---------------------------------------------------------------------------
// fp32 -> bf16 conversion, 7 tensors in one launch (blockIdx.y = job)
// ---------------------------------------------------------------------------
struct CvtJob { const float* s; bf16* d; int n; };
struct CvtArgs { CvtJob j[7]; };

__global__ __launch_bounds__(256) void cvt_k(CvtArgs a) {
    CvtJob job = a.j[blockIdx.y];
    int idx = (blockIdx.x * 256 + threadIdx.x) * 8;
    const int stride = gridDim.x * 256 * 8;
    for (; idx < job.n; idx += stride) {
        float4 f0 = *(const float4*)(job.s + idx);
        float4 f1 = *(const float4*)(job.s + idx + 4);
        short8 o;
        o[0] = (short)f2bf(f0.x); o[1] = (short)f2bf(f0.y);
        o[2] = (short)f2bf(f0.z); o[3] = (short)f2bf(f0.w);
        o[4] = (short)f2bf(f1.x); o[5] = (short)f2bf(f1.y);
        o[6] = (short)f2bf(f1.z); o[7] = (short)f2bf(f1.w);
        *(short8*)(job.d + idx) = o;
    }
}

// ---------------------------------------------------------------------------
// MFMA step over linear [128][32] LDS tiles (global_load_lds staged)
// acc[m][n]: out row = wr*64+m*16+g*4+r (A-row), col = wc*64+n*16+fr (B-row)
// ---------------------------------------------------------------------------
__device__ __forceinline__ void mfma_step32(const bf16* As, const bf16* Bs,
                                            f32x4 acc[4][4],
                                            int wr, int wc, int fr, int g)
{
    short8 af[4], bfv[4];
#pragma unroll
    for (int m = 0; m < 4; ++m)
        af[m] = *(const short8*)(As + (wr * 64 + m * 16 + fr) * 32 + g * 8);
#pragma unroll
    for (int n = 0; n < 4; ++n)
        bfv[n] = *(const short8*)(Bs + (wc * 64 + n * 16 + fr) * 32 + g * 8);
#pragma unroll
    for (int m = 0; m < 4; ++m)
#pragma unroll
        for (int n = 0; n < 4; ++n)
            acc[m][n] = __builtin_amdgcn_mfma_f32_16x16x32_bf16(
                af[m], bfv[n], acc[m][n], 0, 0, 0);
}

// ---------------------------------------------------------------------------
// Multi-job NT GEMM, K = lda = ldb = 1024.  C[M][N] = A@B^T + bias.
// mode 0: fp32 C; mode 1: bf16 C; mode 2: bf16 transposed V-layout write
// ---------------------------------------------------------------------------
struct GemmJob { const bf16* A; const bf16* B; const float* bias; void* C; int mode; };
struct GemmArgs { GemmJob j[3]; };

__global__ __launch_bounds__(256, 3) void gemm_multi_k(GemmArgs args)
{
    __shared__ __align__(16) bf16 As[128 * 32];
    __shared__ __align__(16) bf16 Bs[128 * 32];
    const GemmJob job = args.j[blockIdx.z];
    const int tid = threadIdx.x;
    const int row0 = blockIdx.y * 128;
    const int col0 = blockIdx.x * 128;
    const int lane = tid & 63;
    const int w = tid >> 6, wr = w >> 1, wc = w & 1;
    const int fr = lane & 15, g = lane >> 4;

    const int srow = lane >> 2, scol = (lane & 3) * 8;
    const bf16* Ag = job.A + (size_t)(row0 + w * 32 + srow) * Dsz + scol;
    const bf16* Bg = job.B + (size_t)(col0 + w * 32 + srow) * Dsz + scol;
    const int lofs = __builtin_amdgcn_readfirstlane(w * 32 * 32);
    bf16* Asw = As + lofs;
    bf16* Bsw = Bs + lofs;

    f32x4 acc[4][4];
    const f32x4 vz = {0.f, 0.f, 0.f, 0.f};
#pragma unroll
    for (int m = 0; m < 4; ++m)
#pragma unroll
        for (int n = 0; n < 4; ++n) acc[m][n] = vz;

#pragma unroll 1
    for (int k0 = 0; k0 < Dsz; k0 += 32) {
        gload16(Ag + k0, Asw);
        gload16(Ag + 16 * Dsz + k0, Asw + 16 * 32);
        gload16(Bg + k0, Bsw);
        gload16(Bg + 16 * Dsz + k0, Bsw + 16 * 32);
        __syncthreads();
        mfma_step32(As, Bs, acc, wr, wc, fr, g);
        __syncthreads();
    }

    if (job.mode == 2) {
        bf16* vtp = (bf16*)job.C;
#pragma unroll
        for (int m = 0; m < 4; ++m) {
            const int gi0 = row0 + wr * 64 + m * 16 + g * 4;
            const int bidx = gi0 >> 11, jj = gi0 & 2047;
#pragma unroll
            for (int n = 0; n < 4; ++n) {
                const int gj = col0 + wc * 64 + n * 16 + fr;
                const float bv = job.bias[gj];
                short4v pk;
#pragma unroll
                for (int r = 0; r < 4; ++r)
                    pk[r] = (short)f2bf(acc[m][n][r] + bv);
                const size_t zrow = ((size_t)bidx * 8 + (gj >> 7)) * 128 + (gj & 127);
                *(short4v*)(vtp + zrow * Tsz + jj) = pk;
            }
        }
    } else {
#pragma unroll
        for (int m = 0; m < 4; ++m) {
#pragma unroll
            for (int r = 0; r < 4; ++r) {
                const int gi = row0 + wr * 64 + m * 16 + g * 4 + r;
#pragma unroll
                for (int n = 0; n < 4; ++n) {
                    const int gj = col0 + wc * 64 + n * 16 + fr;
                    float x = acc[m][n][r] + job.bias[gj];
                    if (job.mode == 1)
                        ((bf16*)job.C)[(size_t)gi * Dsz + gj] = __float2bfloat16(x);
                    else
                        ((float*)job.C)[(size_t)gi * Dsz + gj] = x;
                }
            }
        }
    }
}

// ---------------------------------------------------------------------------
// relpos projection: proj[row][c] = dot(tq[row], table[c]), c in 0..4
// ---------------------------------------------------------------------------
__global__ __launch_bounds__(256) void relproj_k(
    const bf16* __restrict__ tq, const float* __restrict__ table,
    float* __restrict__ proj)
{
    const int row  = blockIdx.x * 4 + (threadIdx.x >> 6);
    const int lane = threadIdx.x & 63;
    const bf16* qrow = tq + (size_t)row * Dsz;
    float acc[5] = {0.f, 0.f, 0.f, 0.f, 0.f};
#pragma unroll
    for (int t = 0; t < 4; ++t) {
        const int d = t * 256 + lane * 4;
        short4v q4 = *(const short4v*)(qrow + d);
        float qv[4];
#pragma unroll
        for (int q = 0; q < 4; ++q) qv[q] = bf2f((unsigned short)q4[q]);
#pragma unroll
        for (int c = 0; c < 5; ++c) {
            float4 t4 = *(const float4*)(table + c * Dsz + d);
            acc[c] = fmaf(qv[0], t4.x, acc[c]);
            acc[c] = fmaf(qv[1], t4.y, acc[c]);
            acc[c] = fmaf(qv[2], t4.z, acc[c]);
            acc[c] = fmaf(qv[3], t4.w, acc[c]);
        }
    }
#pragma unroll
    for (int c = 0; c < 5; ++c)
        for (int off = 32; off > 0; off >>= 1)
            acc[c] += __shfl_xor(acc[c], off);
    if (lane == 0) {
#pragma unroll
        for (int c = 0; c < 5; ++c)
            proj[(size_t)row * 8 + c] = acc[c];
    }
}

// ---------------------------------------------------------------------------
// Flash fused attention, 512 threads / 8 waves (2 waves/SIMD).
// Wave (wj, wi): QK^T -> S^T tile [j=128][i=128]: wave owns j-half wj (4 mj
// frags) x i-quarter wi (2 ni frags).  PV: i-quarter wi (2 m2) x d-half wj
// (4 n2).  Q frags hoisted to registers (invariant over kt).
// ---------------------------------------------------------------------------
__global__ __launch_bounds__(512) void flash_pv_k(
    const bf16* __restrict__ tq, const bf16* __restrict__ tk,
    const bf16* __restrict__ vt, const float* __restrict__ proj,
    float* __restrict__ invs_g, bf16* __restrict__ ctx)
{
    __shared__ __align__(16) bf16 Qs[128 * LDK];
    __shared__ __align__(16) bf16 Ks[128 * LDK];
    __shared__ __align__(16) bf16 Vs[128 * LDK];
    __shared__ __align__(16) bf16 Ps[128 * 128];   // XOR-swizzled
    __shared__ float proj_s[5 * 132];
    __shared__ float sums_l[2 * 128];
    __shared__ float inv_t[128];

    const int tid = threadIdx.x;
    const int qt = blockIdx.x, z = blockIdx.y;
    const int b = z >> 3, h = z & 7;
    const int i0 = qt * 128;
    const int lane = tid & 63, w = tid >> 6;
    const int wj = w >> 2;    // 0..1
    const int wi = w & 3;     // 0..3
    const int fr = lane & 15, g = lane >> 4;
    const int srow = tid >> 2, scb = (tid & 3) * 32;

    // stage Q tile + proj rows
    {
        const bf16* qg = tq + (size_t)(b * Tsz + i0 + srow) * Dsz + h * DH + scb;
#pragma unroll
        for (int q = 0; q < 4; ++q)
            *(short8*)(Qs + srow * LDK + scb + q * 8) = *(const short8*)(qg + q * 8);
        if (tid < 128) {
            const float* pr = proj + (size_t)(b * Tsz + i0 + tid) * 8;
#pragma unroll
            for (int c = 0; c < 5; ++c) proj_s[c * 132 + tid] = pr[c];
        }
    }
    __syncthreads();

    // hoist Q fragments (invariant across kt)
    short8 qf[2][4];
#pragma unroll
    for (int ni = 0; ni < 2; ++ni)
#pragma unroll
        for (int ks = 0; ks < 4; ++ks)
            qf[ni][ks] = *(const short8*)(Qs + (wi * 32 + ni * 16 + fr) * LDK + ks * 32 + g * 8);

    f32x4 accp[2][4];
    const f32x4 vz = {0.f, 0.f, 0.f, 0.f};
#pragma unroll
    for (int m = 0; m < 2; ++m)
#pragma unroll
        for (int n = 0; n < 4; ++n) accp[m][n] = vz;
    float rs[2] = {0.f, 0.f};

#pragma unroll 1
    for (int kt = 0; kt < Tsz / 128; ++kt) {
        const int j0 = kt * 128;
        __syncthreads();   // prev K/V/P reads done
        {
            const bf16* kg = tk + (size_t)(b * Tsz + j0 + srow) * Dsz + h * DH + scb;
            const bf16* vg = vt + ((size_t)z * DH + srow) * Tsz + j0 + scb;
            short8 kv[4], vv[4];
#pragma unroll
            for (int q = 0; q < 4; ++q) kv[q] = *(const short8*)(kg + q * 8);
#pragma unroll
            for (int q = 0; q < 4; ++q) vv[q] = *(const short8*)(vg + q * 8);
#pragma unroll
            for (int q = 0; q < 4; ++q) *(short8*)(Ks + srow * LDK + scb + q * 8) = kv[q];
#pragma unroll
            for (int q = 0; q < 4; ++q) *(short8*)(Vs + srow * LDK + scb + q * 8) = vv[q];
        }
        __syncthreads();

        // S^T = K x Q^T : as_[mj][ni], j = wj*64+mj*16+g*4+r, i = wi*32+ni*16+fr
        f32x4 as_[4][2];
#pragma unroll
        for (int m = 0; m < 4; ++m)
#pragma unroll
            for (int n = 0; n < 2; ++n) as_[m][n] = vz;
        __builtin_amdgcn_s_setprio(1);
#pragma unroll
        for (int ks = 0; ks < 4; ++ks) {
            short8 kf[4];
#pragma unroll
            for (int mj = 0; mj < 4; ++mj)
                kf[mj] = *(const short8*)(Ks + (wj * 64 + mj * 16 + fr) * LDK + ks * 32 + g * 8);
#pragma unroll
            for (int mj = 0; mj < 4; ++mj)
#pragma unroll
                for (int ni = 0; ni < 2; ++ni)
                    as_[mj][ni] = __builtin_amdgcn_mfma_f32_16x16x32_bf16(
                        kf[mj], qf[ni][ks], as_[mj][ni], 0, 0, 0);
        }
        __builtin_amdgcn_s_setprio(0);

        // bias + exp + rowsum + pack P -> LDS (swizzled)
        const int dt = kt - qt;
        if (dt <= -2 || dt >= 2) {
            const int c = (dt >= 2) ? 4 : 0;
#pragma unroll
            for (int ni = 0; ni < 2; ++ni) {
                const int il = wi * 32 + ni * 16 + fr;
                const float bias = proj_s[c * 132 + il];
#pragma unroll
                for (int mj = 0; mj < 4; ++mj) {
                    const int jl0 = wj * 64 + mj * 16 + g * 4;
                    short4v pk;
#pragma unroll
                    for (int r = 0; r < 4; ++r) {
                        float p = __expf((as_[mj][ni][r] + bias) * SCALE);
                        rs[ni] += p;
                        pk[r] = (short)f2bf(p);
                    }
                    const int off = ((il * 128 + jl0) * 2) ^ ((il & 7) << 4);
                    *(short4v*)((char*)Ps + off) = pk;
                }
            }
        } else {
#pragma unroll
            for (int ni = 0; ni < 2; ++ni) {
                const int il = wi * 32 + ni * 16 + fr;
#pragma unroll
                for (int mj = 0; mj < 4; ++mj) {
                    const int jl0 = wj * 64 + mj * 16 + g * 4;
                    short4v pk;
#pragma unroll
                    for (int r = 0; r < 4; ++r) {
                        int dd = (jl0 + r + dt * 128) - il;
                        dd = dd < -2 ? -2 : (dd > 2 ? 2 : dd);
                        const float bias = proj_s[(dd + 2) * 132 + il];
                        float p = __expf((as_[mj][ni][r] + bias) * SCALE);
                        rs[ni] += p;
                        pk[r] = (short)f2bf(p);
                    }
                    const int off = ((il * 128 + jl0) * 2) ^ ((il & 7) << 4);
                    *(short4v*)((char*)Ps + off) = pk;
                }
            }
        }
        __syncthreads();   // P visible

        // PV: accp[m2][n2], i = wi*32+m2*16+g*4+r, d = wj*64+n2*16+fr
        __builtin_amdgcn_s_setprio(1);
#pragma unroll
        for (int ks = 0; ks < 4; ++ks) {
            short8 pf[2], vf[4];
#pragma unroll
            for (int m2 = 0; m2 < 2; ++m2) {
                const int il2 = wi * 32 + m2 * 16 + fr;
                const int off = ((il2 * 128 + ks * 32 + g * 8) * 2) ^ ((il2 & 7) << 4);
                pf[m2] = *(const short8*)((char*)Ps + off);
            }
#pragma unroll
            for (int n2 = 0; n2 < 4; ++n2)
                vf[n2] = *(const short8*)(Vs + (wj * 64 + n2 * 16 + fr) * LDK + ks * 32 + g * 8);
#pragma unroll
            for (int m2 = 0; m2 < 2; ++m2)
#pragma unroll
                for (int n2 = 0; n2 < 4; ++n2)
                    accp[m2][n2] = __builtin_amdgcn_mfma_f32_16x16x32_bf16(
                        pf[m2], vf[n2], accp[m2][n2], 0, 0, 0);
        }
        __builtin_amdgcn_s_setprio(0);
    }

    // rowsum: reduce over g, then across the two wj wave-groups via LDS
#pragma unroll
    for (int ni = 0; ni < 2; ++ni) {
        rs[ni] += __shfl_xor(rs[ni], 16);
        rs[ni] += __shfl_xor(rs[ni], 32);
    }
    if (lane < 16) {
#pragma unroll
        for (int ni = 0; ni < 2; ++ni)
            sums_l[wj * 128 + wi * 32 + ni * 16 + fr] = rs[ni];
    }
    __syncthreads();
    if (tid < 128) {
        const float tot = sums_l[tid] + sums_l[128 + tid];
        const float iv = 1.0f / tot;
        inv_t[tid] = iv;
        invs_g[(size_t)z * Tsz + i0 + tid] = iv;
    }
    __syncthreads();

    // ctx epilogue
    bf16* cp = ctx + (size_t)(b * Tsz + i0) * Dsz + h * DH;
#pragma unroll
    for (int m2 = 0; m2 < 2; ++m2) {
#pragma unroll
        for (int r = 0; r < 4; ++r) {
            const int il = wi * 32 + m2 * 16 + g * 4 + r;
            const float iv = inv_t[il];
#pragma unroll
            for (int n2 = 0; n2 < 4; ++n2) {
                const int d = wj * 64 + n2 * 16 + fr;
                cp[(size_t)il * Dsz + d] = __float2bfloat16(accp[m2][n2][r] * iv);
            }
        }
    }
}

// ---------------------------------------------------------------------------
// Merged weights + output-projection kernel.
// z<16: weights tile (swapped S^T layout -> float4 packed stores)
// z==16: output projection block (bid remapped to 8x32 grid)
// ---------------------------------------------------------------------------
__global__ __launch_bounds__(256) void wo_k(
    const bf16* __restrict__ tq, const bf16* __restrict__ tk,
    const float* __restrict__ proj, const float* __restrict__ invs_g,
    float* __restrict__ Wt,
    const bf16* __restrict__ ctx, const bf16* __restrict__ Wob,
    const float* __restrict__ bo, float* __restrict__ out)
{
    __shared__ __align__(16) bf16 As[128 * 32];
    __shared__ __align__(16) bf16 Bs[128 * 32];
    const int tid = threadIdx.x;
    const int lane = tid & 63;
    const int w = tid >> 6, wA = w >> 1, wB = w & 1;
    const int fr = lane & 15, g = lane >> 4;
    const int srow = lane >> 2, scol = (lane & 3) * 8;
    const int lofs = __builtin_amdgcn_readfirstlane(w * 32 * 32);
    bf16* Asw = As + lofs;
    bf16* Bsw = Bs + lofs;

    f32x4 acc[4][4];
    const f32x4 vz = {0.f, 0.f, 0.f, 0.f};
#pragma unroll
    for (int m = 0; m < 4; ++m)
#pragma unroll
        for (int n = 0; n < 4; ++n) acc[m][n] = vz;

    if (blockIdx.z < 16) {
        // ---- weights tile: A = K rows (j, col0 tile), B = Q rows (i, row0) --
        const int z = blockIdx.z, b = z >> 3, h = z & 7;
        const int row0 = blockIdx.y * 128;   // i
        const int col0 = blockIdx.x * 128;   // j
        const bf16* Ag = tk + (size_t)(b * Tsz + col0 + w * 32 + srow) * Dsz + h * DH + scol;
        const bf16* Bg = tq + (size_t)(b * Tsz + row0 + w * 32 + srow) * Dsz + h * DH + scol;

#pragma unroll 1
        for (int k0 = 0; k0 < DH; k0 += 32) {
            gload16(Ag + k0, Asw);
            gload16(Ag + 16 * Dsz + k0, Asw + 16 * 32);
            gload16(Bg + k0, Bsw);
            gload16(Bg + 16 * Dsz + k0, Bsw + 16 * 32);
            __syncthreads();
            mfma_step32(As, Bs, acc, wA, wB, fr, g);
            __syncthreads();
        }

        float* C = Wt + (size_t)z * Tsz * Tsz;
        // block-uniform fast path: all j-i outside [-1,1]?
        const int dmin = col0 - (row0 + 127);
        const int dmax = (col0 + 127) - row0;
        if (dmin >= 2 || dmax <= -2) {
            const int c = (dmin >= 2) ? 4 : 0;
#pragma unroll
            for (int ni = 0; ni < 4; ++ni) {
                const int gi = row0 + wB * 64 + ni * 16 + fr;
                const float iv = invs_g[(size_t)z * Tsz + gi];
                const float bias = proj[(size_t)(b * Tsz + gi) * 8 + c];
#pragma unroll
                for (int mj = 0; mj < 4; ++mj) {
                    const int jb = col0 + wA * 64 + mj * 16 + g * 4;
                    float4 o;
                    float* op = (float*)&o;
#pragma unroll
                    for (int r = 0; r < 4; ++r)
                        op[r] = __expf((acc[mj][ni][r] + bias) * SCALE) * iv;
                    *(float4*)(C + (size_t)gi * Tsz + jb) = o;
                }
            }
        } else {
#pragma unroll
            for (int ni = 0; ni < 4; ++ni) {
                const int gi = row0 + wB * 64 + ni * 16 + fr;
                const float iv = invs_g[(size_t)z * Tsz + gi];
                const float* prow = proj + (size_t)(b * Tsz + gi) * 8;
#pragma unroll
                for (int mj = 0; mj < 4; ++mj) {
                    const int jb = col0 + wA * 64 + mj * 16 + g * 4;
                    float4 o;
                    float* op = (float*)&o;
#pragma unroll
                    for (int r = 0; r < 4; ++r) {
                        int rel = (jb + r) - gi;
                        rel = rel < -2 ? -2 : (rel > 2 ? 2 : rel);
                        op[r] = __expf((acc[mj][ni][r] + prow[rel + 2]) * SCALE) * iv;
                    }
                    *(float4*)(C + (size_t)gi * Tsz + jb) = o;
                }
            }
        }
    } else {
        // ---- output projection: out[4096,1024] = ctx @ Wo^T + bo (fp32) ----
        const int bid = blockIdx.y * 16 + blockIdx.x;
        const int row0 = (bid >> 3) * 128;
        const int col0 = (bid & 7) * 128;
        const bf16* Ag = ctx + (size_t)(row0 + w * 32 + srow) * Dsz + scol;
        const bf16* Bg = Wob + (size_t)(col0 + w * 32 + srow) * Dsz + scol;

#pragma unroll 1
        for (int k0 = 0; k0 < Dsz; k0 += 32) {
            gload16(Ag + k0, Asw);
            gload16(Ag + 16 * Dsz + k0, Asw + 16 * 32);
            gload16(Bg + k0, Bsw);
            gload16(Bg + 16 * Dsz + k0, Bsw + 16 * 32);
            __syncthreads();
            mfma_step32(As, Bs, acc, wA, wB, fr, g);
            __syncthreads();
        }

#pragma unroll
        for (int m = 0; m < 4; ++m) {
#pragma unroll
            for (int r = 0; r < 4; ++r) {
                const int gi = row0 + wA * 64 + m * 16 + g * 4 + r;
#pragma unroll
                for (int n = 0; n < 4; ++n) {
                    const int gj = col0 + wB * 64 + n * 16 + fr;
                    out[(size_t)gi * Dsz + gj] = acc[m][n][r] + bo[gj];
                }
            }
        }
    }
}

// ---------------------------------------------------------------------------
extern "C" void kernel_launch(void* const* d_in, const int* in_sizes, int n_in,
                              void* d_out, int out_size, void* d_ws, size_t ws_size,
                              hipStream_t stream)
{
    const float* query  = (const float*)d_in[0];
    const float* keys   = (const float*)d_in[1];
    const float* values = (const float*)d_in[2];
    const float* Wq = (const float*)d_in[3];
    const float* bq = (const float*)d_in[4];
    const float* Wk = (const float*)d_in[5];
    const float* bk = (const float*)d_in[6];
    const float* Wv = (const float*)d_in[7];
    const float* bv = (const float*)d_in[8];
    const float* Wo = (const float*)d_in[9];
    const float* bo = (const float*)d_in[10];
    const float* table = (const float*)d_in[11];

    float* out     = (float*)d_out;                      // B*T*D fp32
    float* weights = out + (size_t)Bsz * Tsz * Dsz;      // B*H*T*T fp32

    const size_t NTD = (size_t)Bsz * Tsz * Dsz;          // 4M elems
    char* wp = (char*)d_ws;
    bf16* qb  = (bf16*)(wp);
    bf16* kb  = (bf16*)(wp + 8  * 1024 * 1024);          // reused as ctx
    bf16* vb  = (bf16*)(wp + 16 * 1024 * 1024);
    bf16* tq  = (bf16*)(wp + 24 * 1024 * 1024);
    bf16* tk  = (bf16*)(wp + 32 * 1024 * 1024);
    bf16* vt  = (bf16*)(wp + 40 * 1024 * 1024);          // V in [z][d][j] layout
    bf16* Wqb = (bf16*)(wp + 48 * 1024 * 1024);
    bf16* Wkb = (bf16*)(wp + 50 * 1024 * 1024);
    bf16* Wvb = (bf16*)(wp + 52 * 1024 * 1024);
    bf16* Wob = (bf16*)(wp + 54 * 1024 * 1024);
    float* proj   = (float*)(wp + 56 * 1024 * 1024);
    float* invs_g = (float*)(wp + 57 * 1024 * 1024);
    bf16* ctx = kb;

    const dim3 blk(256);

    CvtArgs ca;
    ca.j[0] = { query,  qb,  (int)NTD };
    ca.j[1] = { keys,   kb,  (int)NTD };
    ca.j[2] = { values, vb,  (int)NTD };
    ca.j[3] = { Wq, Wqb, Dsz * Dsz };
    ca.j[4] = { Wk, Wkb, Dsz * Dsz };
    ca.j[5] = { Wv, Wvb, Dsz * Dsz };
    ca.j[6] = { Wo, Wob, Dsz * Dsz };
    cvt_k<<<dim3(1024, 7), blk, 0, stream>>>(ca);

    // fused Q/K/V projections; V written directly in transposed [z][d][j] form
    GemmArgs ga;
    ga.j[0] = { qb, Wqb, bq, tq, 1 };
    ga.j[1] = { kb, Wkb, bk, tk, 1 };
    ga.j[2] = { vb, Wvb, bv, vt, 2 };
    gemm_multi_k<<<dim3(Dsz / 128, Bsz * Tsz / 128, 3), blk, 0, stream>>>(ga);

    relproj_k<<<dim3(Bsz * Tsz / 4), blk, 0, stream>>>(tq, table, proj);

    // fused attention: ctx + row-sum inverses (no S*S traffic)
    flash_pv_k<<<dim3(Tsz / 128, Bsz * Hn), dim3(512), 0, stream>>>(
        tq, tk, vt, proj, invs_g, ctx);

    // merged weights write + output projection (out-proj blocks fill in
    // behind the write-bound weights blocks)
    wo_k<<<dim3(16, 16, 17), blk, 0, stream>>>(
        tq, tk, proj, invs_g, weights, ctx, Wob, bo, out);
}